// Round 1
// 24504.735 us; speedup vs baseline: 1.4203x; 1.4203x over previous
//
#include <hip/hip_runtime.h>
#include <hip/hip_bf16.h>
#include <cstddef>
#include <cstdint>

// Problem dims (fixed): T=512, B=64, D=H=512, gates = 4*H = 2048
#define TT 512
#define BB 64
#define HH 512

typedef __attribute__((ext_vector_type(8))) short bf16x8;   // 8 bf16 = 4 VGPRs
typedef __attribute__((ext_vector_type(4))) float f32x4;    // MFMA C/D

__device__ __forceinline__ float sigf(float x) { return 1.0f / (1.0f + __expf(-x)); }
__device__ __forceinline__ float tanhfast(float x) { return 2.0f / (1.0f + __expf(-2.0f * x)) - 1.0f; }

// fp32 -> bf16 (round-nearest-even), as raw short
__device__ __forceinline__ short f2bf(float x) {
  uint32_t u = __float_as_uint(x);
  u += 0x7FFFu + ((u >> 16) & 1u);
  return (short)(u >> 16);
}

// Adaptive 8-element fragment load (element-indexed). isbf: 1 = bf16, 0 = fp32.
__device__ __forceinline__ bf16x8 ldab(const void* base, size_t e, int isbf) {
  if (isbf) return *(const bf16x8*)((const short*)base + e);
  const float* f = (const float*)base + e;
  float4 a = *(const float4*)f;
  float4 b = *(const float4*)(f + 4);
  bf16x8 r;
  r[0] = f2bf(a.x); r[1] = f2bf(a.y); r[2] = f2bf(a.z); r[3] = f2bf(a.w);
  r[4] = f2bf(b.x); r[5] = f2bf(b.y); r[6] = f2bf(b.z); r[7] = f2bf(b.w);
  return r;
}

__device__ __forceinline__ float ldsc(const void* base, size_t e, int isbf) {
  if (isbf) return (float)((const __hip_bfloat16*)base)[e];
  return ((const float*)base)[e];
}

__device__ __forceinline__ void stsc(void* base, size_t e, float v, int isbf) {
  if (isbf) ((__hip_bfloat16*)base)[e] = __float2bfloat16(v);
  else      ((float*)base)[e] = v;
}

// ---------------------------------------------------------------------------
// Dtype sniffer (unchanged, proven): majority-vote on bf16-pair exponent bits.
// ---------------------------------------------------------------------------
__global__ __launch_bounds__(256) void sniff(const unsigned int* __restrict__ x,
                                             int* __restrict__ flag) {
  __shared__ int cnt[256];
  int c = 0;
#pragma unroll
  for (int i = 0; i < 16; ++i) {
    unsigned w = x[threadIdx.x * 16 + i];
    unsigned e = (w >> 7) & 0xFFu;
    c += (e >= 110u && e <= 140u) ? 1 : 0;
  }
  cnt[threadIdx.x] = c;
  __syncthreads();
  for (int s = 128; s > 0; s >>= 1) {
    if ((int)threadIdx.x < s) cnt[threadIdx.x] += cnt[threadIdx.x + s];
    __syncthreads();
  }
  if (threadIdx.x == 0) flag[0] = (cnt[0] > 2048) ? 1 : 0;
}

// ---------------------------------------------------------------------------
// Device-scope grid barrier. All blocks of the persistent kernels are
// co-resident (grid <= 128 on 256 CUs, 1 block/CU resources). Monotonic
// generation counter; agent-scope fences give cross-XCD visibility for the
// h-state exchanged through global memory.
// ---------------------------------------------------------------------------
__device__ __forceinline__ void gridbar(int* bar, int nblk, int gen) {
  __syncthreads();
  if (threadIdx.x == 0) {
    __threadfence();   // release: make this block's global stores visible
    __hip_atomic_fetch_add(bar, 1, __ATOMIC_RELAXED, __HIP_MEMORY_SCOPE_AGENT);
    while (__hip_atomic_load(bar, __ATOMIC_RELAXED, __HIP_MEMORY_SCOPE_AGENT) < nblk * gen)
      __builtin_amdgcn_s_sleep(1);
    __threadfence();   // acquire: invalidate stale cached lines
  }
  __syncthreads();
}

// ---------------------------------------------------------------------------
// Elementwise convert-to-bf16 (Plan A: x -> x_bf). Copies if already bf16.
// ---------------------------------------------------------------------------
__global__ __launch_bounds__(256) void conv_bf16(const void* __restrict__ src,
                                                 __hip_bfloat16* __restrict__ dst,
                                                 const int* __restrict__ flagp,
                                                 size_t n8) {
  const int isbf = flagp[0];
  for (size_t i = (size_t)blockIdx.x * 256 + threadIdx.x; i < n8;
       i += (size_t)gridDim.x * 256) {
    bf16x8 v = ldab(src, i * 8, isbf);
    *(bf16x8*)((short*)dst + i * 8) = v;
  }
}

// ---------------------------------------------------------------------------
// Stash fill (Plans B/C/D): snapshot hazard halves of this pass's b-columns
// from pristine y0 (in out) into bf16 stash. Same math as proven stash_copy.
// stashF[row][lb][k] = out[row      ][b][k]      (rows 0..255, fwd half)
// stashB[row][lb][k] = out[256+row  ][b][512+k]  (rows 256..511, bwd half)
// ---------------------------------------------------------------------------
__global__ __launch_bounds__(256) void stash_fill(
    const void* __restrict__ out,
    __hip_bfloat16* __restrict__ stashF,
    __hip_bfloat16* __restrict__ stashB,
    const int* __restrict__ flagp,
    int bcount, int pass_off)
{
  const int isbf = flagp[0];
  const size_t total8 = (size_t)2 * 256 * bcount * HH / 8;
  for (size_t i = (size_t)blockIdx.x * 256 + threadIdx.x; i < total8;
       i += (size_t)gridDim.x * 256) {
    const size_t idx = i * 8;
    const int k = (int)(idx & 511);
    const size_t r = idx >> 9;
    const int lb = (int)(r % bcount);
    const size_t rr = r / bcount;
    const int row = (int)(rr & 255);
    const bool isB = rr >= 256;
    const size_t src = ((size_t)(isB ? (256 + row) : row) * BB + pass_off + lb) * 1024 +
                       (isB ? HH : 0) + k;
    bf16x8 v = ldab(out, src, isbf);
    __hip_bfloat16* dst = (isB ? stashB : stashF) + ((size_t)row * bcount + lb) * HH + k;
    *(bf16x8*)(void*)dst = v;
  }
}

// ---------------------------------------------------------------------------
// PERSISTENT LAYER 0. Grid 128 = dir(2) x jtile(32) x bhalf(2), 256 thr.
// Wave g = gate g for rows jt*16..+16; all weights live in VGPRs
// (wih[16] + whh[16] frags = 128 VGPRs); c-state lives in regs; h double-
// buffered in ws (bf16, pre-masked with consumer's mask). One barrier/step.
// ---------------------------------------------------------------------------
__global__ __launch_bounds__(256, 1) void l0_persist(
    const void* __restrict__ x,          // original x (dtype per flag)
    const void* __restrict__ xbf,        // Plan A: pre-converted bf16 x
    int use_xbf,
    const void* __restrict__ Wih_f, const void* __restrict__ Whh_f, const void* __restrict__ bias_f,
    const void* __restrict__ Wih_b, const void* __restrict__ Whh_b, const void* __restrict__ bias_b,
    __hip_bfloat16* __restrict__ hb,     // [2 buf][2 dir][64][512] bf16
    const int* __restrict__ lens,
    void* __restrict__ ydst,             // Plan A: y0_bf (bf16); else out (dtype)
    int y_is_bf,
    const int* __restrict__ flagp,
    int* __restrict__ bar)
{
  const int isbf = flagp[0];
  const int bx = blockIdx.x;
  const int d  = bx >> 6;
  const int jt = (bx >> 1) & 31;
  const int bh = bx & 1;

  const void* Wih  = d ? Wih_b  : Wih_f;
  const void* Whh  = d ? Whh_b  : Whh_f;
  const void* bias = d ? bias_b : bias_f;

  const int tid  = threadIdx.x;
  const int lane = tid & 63;
  const int g    = tid >> 6;      // wave = gate
  const int nm   = lane & 15;
  const int kq   = (lane >> 4) * 8;

  // ---- one-time: weights -> registers (converted if fp32) ----
  bf16x8 wih[16], whh[16];
  {
    const size_t arow = (size_t)(g * HH + jt * 16 + nm) * HH + kq;
#pragma unroll
    for (int ks = 0; ks < 16; ++ks) {
      wih[ks] = ldab(Wih, arow + ks * 32, isbf);
      whh[ks] = ldab(Whh, arow + ks * 32, isbf);
    }
  }

  const void* xs = use_xbf ? xbf : x;
  const int   xf = use_xbf ? 1 : isbf;

  // ---- update-phase statics (thread -> (ub, j-pair), fixed across steps) ----
  const int ub  = tid >> 3;              // local batch 0..31
  const int jq  = (tid & 7) * 2;         // j pair base 0..14
  const int b_g = bh * 32 + ub;          // global batch
  const int j_g = jt * 16 + jq;
  const int len = lens[b_g];
  float bias_r[4][2];
#pragma unroll
  for (int q = 0; q < 4; ++q) {
    bias_r[q][0] = ldsc(bias, q * HH + j_g, isbf);
    bias_r[q][1] = ldsc(bias, q * HH + j_g + 1, isbf);
  }
  float c0 = 0.f, c1 = 0.f;

  const int brow0 = bh * 32 + nm;        // MFMA B batch rows
  const int brow1 = brow0 + 16;

  __shared__ float gx[4][16][33];

  for (int s = 0; s < TT; ++s) {
    const int t_eff = d ? (TT - 1 - s) : s;
    const __hip_bfloat16* hcur = hb + ((size_t)(s & 1) * 2 + d) * (size_t)(BB * HH);

    f32x4 acc0 = {0.f, 0.f, 0.f, 0.f};
    f32x4 acc1 = {0.f, 0.f, 0.f, 0.f};
    const size_t xo0 = ((size_t)t_eff * BB + brow0) * HH + kq;
    const size_t xo1 = ((size_t)t_eff * BB + brow1) * HH + kq;
#pragma unroll
    for (int ks = 0; ks < 16; ++ks) {
      acc0 = __builtin_amdgcn_mfma_f32_16x16x32_bf16(wih[ks], ldab(xs, xo0 + ks * 32, xf), acc0, 0, 0, 0);
      acc1 = __builtin_amdgcn_mfma_f32_16x16x32_bf16(wih[ks], ldab(xs, xo1 + ks * 32, xf), acc1, 0, 0, 0);
    }
    const short* h0 = (const short*)hcur + (size_t)brow0 * HH + kq;
#pragma unroll
    for (int ks = 0; ks < 16; ++ks) {
      acc0 = __builtin_amdgcn_mfma_f32_16x16x32_bf16(whh[ks], *(const bf16x8*)(h0 + ks * 32), acc0, 0, 0, 0);
      acc1 = __builtin_amdgcn_mfma_f32_16x16x32_bf16(whh[ks], *(const bf16x8*)(h0 + 16 * HH + ks * 32), acc1, 0, 0, 0);
    }
    {
      const int quad = lane >> 4;
#pragma unroll
      for (int r = 0; r < 4; ++r) {
        gx[g][quad * 4 + r][nm]      = acc0[r];
        gx[g][quad * 4 + r][16 + nm] = acc1[r];
      }
    }
    __syncthreads();

    // ---- fused update: nonlinearity, reg c-state, h/y writes ----
    {
      const float m = (t_eff < len) ? 1.0f : 0.0f;
      const int tn = d ? (t_eff - 1) : (t_eff + 1);
      const float mn = (tn >= 0 && tn < len) ? 1.0f : 0.0f;
      __hip_bfloat16* hnxt = hb + ((size_t)((s + 1) & 1) * 2 + d) * (size_t)(BB * HH) +
                             (size_t)b_g * HH + j_g;
      const size_t yb = ((size_t)t_eff * BB + b_g) * 1024 + (size_t)d * HH + j_g;
#define L0UPD(E, CREF) do { \
      const int jl = jq + (E); \
      float vi = gx[0][jl][ub] + bias_r[0][E]; \
      float vf = gx[1][jl][ub] + bias_r[1][E]; \
      float vg = gx[2][jl][ub] + bias_r[2][E]; \
      float vo = gx[3][jl][ub] + bias_r[3][E]; \
      const float cold = (CREF) * m; \
      const float c2 = sigf(vf) * cold + sigf(vi) * tanhfast(vg); \
      const float h2 = sigf(vo) * tanhfast(c2); \
      (CREF) = c2; \
      hnxt[E] = __float2bfloat16(h2 * mn); \
      if (y_is_bf) ((__hip_bfloat16*)ydst)[yb + (E)] = __float2bfloat16(h2 * m); \
      else stsc(ydst, yb + (E), h2 * m, isbf); \
    } while (0)
      L0UPD(0, c0);
      L0UPD(1, c1);
#undef L0UPD
    }
    if (s != TT - 1) gridbar(bar, 128, s + 1);
  }
}

// ---------------------------------------------------------------------------
// PERSISTENT LAYER 1. Grid 64*nbh = dir(2) x jtile(32) x bhalf(nbh).
// Weights in VGPRs: wih[32] (K=1024) + whh[16] = 192 VGPRs/wave.
// Plan A (use_y0): reads pristine bf16 y0; out never read -> 1 barrier/step.
// Plans B/C/D: reads out (adaptive dtype) + bf16 stash for clobbered halves;
// in-place out writes require a mid-step barrier (all out-reads before any
// out-write) + end-step barrier (h/out writes before next step's reads).
// ---------------------------------------------------------------------------
__global__ __launch_bounds__(256, 1) void l1_persist(
    const void* __restrict__ Wih_f, const void* __restrict__ Whh_f, const void* __restrict__ bias_f,
    const void* __restrict__ Wih_b, const void* __restrict__ Whh_b, const void* __restrict__ bias_b,
    const void* __restrict__ ysrc,   // out (B/C/D) or y0_bf (A), row stride 1024
    int use_y0,
    const __hip_bfloat16* __restrict__ stashF,
    const __hip_bfloat16* __restrict__ stashB,
    __hip_bfloat16* __restrict__ hb,
    const int* __restrict__ lens,
    void* __restrict__ out,
    const int* __restrict__ flagp,
    int* __restrict__ bar,
    int pass_off, int nb, int nbh, int bcount)
{
  const int isbf = flagp[0];
  const int bx = blockIdx.x;
  const int nblk = 64 * nbh;
  const int d   = bx / (32 * nbh);
  const int rem = bx % (32 * nbh);
  const int jt  = rem / nbh;
  const int bh  = rem % nbh;

  const void* Wih  = d ? Wih_b  : Wih_f;
  const void* Whh  = d ? Whh_b  : Whh_f;
  const void* bias = d ? bias_b : bias_f;

  const int tid  = threadIdx.x;
  const int lane = tid & 63;
  const int g    = tid >> 6;
  const int nm   = lane & 15;
  const int kq   = (lane >> 4) * 8;

  // ---- one-time: weights -> registers ----
  bf16x8 wih[32], whh[16];
  {
    const size_t arow_ih = (size_t)(g * HH + jt * 16 + nm) * 1024 + kq;
    const size_t arow_hh = (size_t)(g * HH + jt * 16 + nm) * HH + kq;
#pragma unroll
    for (int ks = 0; ks < 32; ++ks) wih[ks] = ldab(Wih, arow_ih + ks * 32, isbf);
#pragma unroll
    for (int ks = 0; ks < 16; ++ks) whh[ks] = ldab(Whh, arow_hh + ks * 32, isbf);
  }

  const bool NBT2 = (nb == 32);
  const int lb0 = bh * nb + nm;          // local batch row (bt0)
  const int srcfl = use_y0 ? 1 : isbf;

  const int ub  = NBT2 ? (tid >> 3) : (tid >> 4);
  const int jq  = NBT2 ? ((tid & 7) * 2) : (tid & 15);
  const int b_g = pass_off + bh * nb + ub;
  const int j_g = jt * 16 + jq;
  const int len = lens[b_g];
  float bias_r[4][2];
#pragma unroll
  for (int q = 0; q < 4; ++q) {
    bias_r[q][0] = ldsc(bias, q * HH + j_g, isbf);
    bias_r[q][1] = NBT2 ? ldsc(bias, q * HH + j_g + 1, isbf) : 0.f;
  }
  float c0 = 0.f, c1 = 0.f;

  __shared__ float gx[4][16][33];

  for (int s = 0; s < TT; ++s) {
    const int t_eff = d ? (TT - 1 - s) : s;

    // resolve per-half input sources (wave-uniform scalars)
    const void* pl; size_t ol; int stl; int fl;
    const void* ph; size_t oh; int sth; int fh;
    if (d == 0) {
      pl = ysrc; ol = ((size_t)t_eff * BB + pass_off) * 1024; stl = 1024; fl = srcfl;
      if (use_y0 || s < 256) { ph = ysrc; oh = ol + HH; sth = 1024; fh = srcfl; }
      else { ph = stashB; oh = (size_t)(s - 256) * bcount * HH; sth = HH; fh = 1; }
    } else {
      ph = ysrc; oh = ((size_t)t_eff * BB + pass_off) * 1024 + HH; sth = 1024; fh = srcfl;
      if (use_y0 || s < 256) { pl = ysrc; ol = ((size_t)t_eff * BB + pass_off) * 1024; stl = 1024; fl = srcfl; }
      else { pl = stashF; ol = (size_t)t_eff * bcount * HH; stl = HH; fl = 1; }
    }

    f32x4 acc0 = {0.f, 0.f, 0.f, 0.f};
    f32x4 acc1 = {0.f, 0.f, 0.f, 0.f};
#pragma unroll
    for (int ks = 0; ks < 16; ++ks) {
      const size_t krel = (size_t)ks * 32 + kq;
      acc0 = __builtin_amdgcn_mfma_f32_16x16x32_bf16(wih[ks], ldab(pl, ol + (size_t)lb0 * stl + krel, fl), acc0, 0, 0, 0);
      if (NBT2)
        acc1 = __builtin_amdgcn_mfma_f32_16x16x32_bf16(wih[ks], ldab(pl, ol + (size_t)(lb0 + 16) * stl + krel, fl), acc1, 0, 0, 0);
    }
#pragma unroll
    for (int ks = 0; ks < 16; ++ks) {
      const size_t krel = (size_t)ks * 32 + kq;
      acc0 = __builtin_amdgcn_mfma_f32_16x16x32_bf16(wih[16 + ks], ldab(ph, oh + (size_t)lb0 * sth + krel, fh), acc0, 0, 0, 0);
      if (NBT2)
        acc1 = __builtin_amdgcn_mfma_f32_16x16x32_bf16(wih[16 + ks], ldab(ph, oh + (size_t)(lb0 + 16) * sth + krel, fh), acc1, 0, 0, 0);
    }
    const __hip_bfloat16* hcur = hb + ((size_t)(s & 1) * 2 + d) * (size_t)(BB * HH);
    const short* h0 = (const short*)hcur + (size_t)(pass_off + bh * nb + nm) * HH + kq;
#pragma unroll
    for (int ks = 0; ks < 16; ++ks) {
      acc0 = __builtin_amdgcn_mfma_f32_16x16x32_bf16(whh[ks], *(const bf16x8*)(h0 + ks * 32), acc0, 0, 0, 0);
      if (NBT2)
        acc1 = __builtin_amdgcn_mfma_f32_16x16x32_bf16(whh[ks], *(const bf16x8*)(h0 + 16 * HH + ks * 32), acc1, 0, 0, 0);
    }
    {
      const int quad = lane >> 4;
#pragma unroll
      for (int r = 0; r < 4; ++r) {
        gx[g][quad * 4 + r][nm] = acc0[r];
        if (NBT2) gx[g][quad * 4 + r][16 + nm] = acc1[r];
      }
    }
    // In-place plans: all out-reads (MFMA loop) must complete grid-wide
    // before any out-write below.
    if (!use_y0) gridbar(bar, nblk, 2 * s + 1);
    else __syncthreads();

    {
      const float m = (t_eff < len) ? 1.0f : 0.0f;
      const int tn = d ? (t_eff - 1) : (t_eff + 1);
      const float mn = (tn >= 0 && tn < len) ? 1.0f : 0.0f;
      __hip_bfloat16* hnxt = hb + ((size_t)((s + 1) & 1) * 2 + d) * (size_t)(BB * HH) +
                             (size_t)b_g * HH + j_g;
      const size_t yb = ((size_t)t_eff * BB + b_g) * 1024 + (size_t)d * HH + j_g;
#define L1UPD(E, CREF) do { \
      const int jl = jq + (E); \
      float vi = gx[0][jl][ub] + bias_r[0][E]; \
      float vf = gx[1][jl][ub] + bias_r[1][E]; \
      float vg = gx[2][jl][ub] + bias_r[2][E]; \
      float vo = gx[3][jl][ub] + bias_r[3][E]; \
      const float cold = (CREF) * m; \
      const float c2 = sigf(vf) * cold + sigf(vi) * tanhfast(vg); \
      const float h2 = sigf(vo) * tanhfast(c2); \
      (CREF) = c2; \
      hnxt[E] = __float2bfloat16(h2 * mn); \
      stsc(out, yb + (E), h2 * m, isbf); \
    } while (0)
      L1UPD(0, c0);
      if (NBT2) L1UPD(1, c1);
#undef L1UPD
    }
    if (s != TT - 1) gridbar(bar, nblk, use_y0 ? (s + 1) : (2 * s + 2));
  }
}

// ---------------------------------------------------------------------------
extern "C" void kernel_launch(void* const* d_in, const int* in_sizes, int n_in,
                              void* d_out, int out_size, void* d_ws, size_t ws_size,
                              hipStream_t stream) {
  (void)in_sizes; (void)n_in; (void)out_size;
  const void* x     = d_in[0];
  const int*  lens  = (const int*)d_in[1];
  const void* fWih0 = d_in[2];
  const void* fWhh0 = d_in[3];
  const void* fb0   = d_in[4];
  const void* bWih0 = d_in[5];
  const void* bWhh0 = d_in[6];
  const void* bb0   = d_in[7];
  const void* fWih1 = d_in[8];
  const void* fWhh1 = d_in[9];
  const void* fb1   = d_in[10];
  const void* bWih1 = d_in[11];
  const void* bWhh1 = d_in[12];
  const void* bb1   = d_in[13];
  void* out = d_out;

  // --- ws layout: [flag 128][bar 128][hb 256KB][plan region] ---
  char* w = (char*)d_ws;
  int* flagp = (int*)w;
  int* bar   = (int*)(w + 128);
  __hip_bfloat16* hb = (__hip_bfloat16*)(w + 256);
  const size_t HBYTES = (size_t)2 * 2 * BB * HH * sizeof(__hip_bfloat16); // 262144
  char* dyn = w + 256 + HBYTES;
  const size_t avail = (ws_size > 256 + HBYTES) ? (ws_size - 256 - HBYTES) : 0;

  const size_t XBF = (size_t)TT * BB * HH * 2;     // 32 MB bf16 x
  const size_t Y0B = (size_t)TT * BB * 1024 * 2;   // 64 MB bf16 y0

  sniff<<<1, 256, 0, stream>>>((const unsigned int*)x, flagp);

  if (avail >= XBF + Y0B) {
    // ---- Plan A: separate bf16 y0, no stash, 1 barrier/step in layer 1 ----
    __hip_bfloat16* xbf = (__hip_bfloat16*)dyn;
    __hip_bfloat16* y0  = (__hip_bfloat16*)(dyn + XBF);
    conv_bf16<<<2048, 256, 0, stream>>>(x, xbf, flagp, (size_t)TT * BB * HH / 8);
    hipMemsetAsync(hb, 0, HBYTES, stream);
    hipMemsetAsync(bar, 0, sizeof(int), stream);
    l0_persist<<<128, 256, 0, stream>>>(x, xbf, 1, fWih0, fWhh0, fb0, bWih0, bWhh0, bb0,
                                        hb, lens, y0, 1, flagp, bar);
    hipMemsetAsync(hb, 0, HBYTES, stream);
    hipMemsetAsync(bar, 0, sizeof(int), stream);
    l1_persist<<<128, 256, 0, stream>>>(fWih1, fWhh1, fb1, bWih1, bWhh1, bb1,
                                        y0, 1, nullptr, nullptr, hb, lens, out, flagp, bar,
                                        0, 32, 2, 64);
  } else {
    // ---- Plans B/C/D: in-place out + bf16 stash of hazard halves ----
    const int bcount = (avail >= (size_t)64 * 524288) ? 64 :
                       (avail >= (size_t)32 * 524288) ? 32 : 16;
    const int nb  = (bcount == 64) ? 32 : 16;
    const int nbh = (bcount == 16) ? 1 : 2;
    __hip_bfloat16* stashF = (__hip_bfloat16*)dyn;
    __hip_bfloat16* stashB = stashF + (size_t)256 * bcount * HH;

    hipMemsetAsync(hb, 0, HBYTES, stream);
    hipMemsetAsync(bar, 0, sizeof(int), stream);
    l0_persist<<<128, 256, 0, stream>>>(x, nullptr, 0, fWih0, fWhh0, fb0, bWih0, bWhh0, bb0,
                                        hb, lens, out, 0, flagp, bar);
    const int P = 64 / bcount;
    for (int p = 0; p < P; ++p) {
      stash_fill<<<1024, 256, 0, stream>>>(out, stashF, stashB, flagp, bcount, p * bcount);
      hipMemsetAsync(hb, 0, HBYTES, stream);
      hipMemsetAsync(bar, 0, sizeof(int), stream);
      l1_persist<<<64 * nbh, 256, 0, stream>>>(fWih1, fWhh1, fb1, bWih1, bWhh1, bb1,
                                               out, 0, stashF, stashB, hb, lens, out, flagp, bar,
                                               p * bcount, nb, nbh, bcount);
    }
  }
}

// Round 2
// 14811.723 us; speedup vs baseline: 2.3497x; 1.6544x over previous
//
#include <hip/hip_runtime.h>
#include <hip/hip_bf16.h>
#include <cstddef>
#include <cstdint>

// Problem dims (fixed): T=512, B=64, D=H=512, gates = 4*H = 2048
#define TT 512
#define BB 64
#define HH 512

typedef __attribute__((ext_vector_type(8))) short bf16x8;   // 8 bf16 = 4 VGPRs
typedef __attribute__((ext_vector_type(4))) float f32x4;    // MFMA C/D
typedef __attribute__((ext_vector_type(4))) int   i32x4;    // 16B staging reg

#define MFMA __builtin_amdgcn_mfma_f32_16x16x32_bf16

__device__ __forceinline__ float sigf(float x) { return 1.0f / (1.0f + __expf(-x)); }
__device__ __forceinline__ float tanhfast(float x) { return 2.0f / (1.0f + __expf(-2.0f * x)) - 1.0f; }

// fp32 -> bf16 (round-nearest-even), as raw short
__device__ __forceinline__ short f2bf(float x) {
  uint32_t u = __float_as_uint(x);
  u += 0x7FFFu + ((u >> 16) & 1u);
  return (short)(u >> 16);
}

// Adaptive 8-element fragment load (element-indexed). isbf: 1 = bf16, 0 = fp32.
// With compile-time isbf the branch folds away.
__device__ __forceinline__ bf16x8 ldab(const void* base, size_t e, int isbf) {
  if (isbf) return *(const bf16x8*)((const short*)base + e);
  const float* f = (const float*)base + e;
  float4 a = *(const float4*)f;
  float4 b = *(const float4*)(f + 4);
  bf16x8 r;
  r[0] = f2bf(a.x); r[1] = f2bf(a.y); r[2] = f2bf(a.z); r[3] = f2bf(a.w);
  r[4] = f2bf(b.x); r[5] = f2bf(b.y); r[6] = f2bf(b.z); r[7] = f2bf(b.w);
  return r;
}

__device__ __forceinline__ float ldsc(const void* base, size_t e, int isbf) {
  if (isbf) return (float)((const __hip_bfloat16*)base)[e];
  return ((const float*)base)[e];
}

// ---------------------------------------------------------------------------
// Dtype sniffer (proven): majority-vote on bf16-pair exponent bits.
// ---------------------------------------------------------------------------
__global__ __launch_bounds__(256) void sniff(const unsigned int* __restrict__ x,
                                             int* __restrict__ flag) {
  __shared__ int cnt[256];
  int c = 0;
#pragma unroll
  for (int i = 0; i < 16; ++i) {
    unsigned w = x[threadIdx.x * 16 + i];
    unsigned e = (w >> 7) & 0xFFu;
    c += (e >= 110u && e <= 140u) ? 1 : 0;
  }
  cnt[threadIdx.x] = c;
  __syncthreads();
  for (int s = 128; s > 0; s >>= 1) {
    if ((int)threadIdx.x < s) cnt[threadIdx.x] += cnt[threadIdx.x + s];
    __syncthreads();
  }
  if (threadIdx.x == 0) flag[0] = (cnt[0] > 2048) ? 1 : 0;
}

// ---------------------------------------------------------------------------
// Slot-based grid barrier: NO RMW contention, NO cache-invalidating fences.
// Arrival: per-block relaxed agent store of the generation into its own slot.
// Block 0: lanes < nblk watch slots in parallel, then broadcast gflag = gen.
// Others: poll gflag (single word). Entry __syncthreads drains every thread's
// outstanding stores (compiler emits s_waitcnt vmcnt(0) before s_barrier), so
// the write-through h stores are at the coherent point before arrival.
// ---------------------------------------------------------------------------
__device__ __forceinline__ void slotbar(int* __restrict__ slots, int* __restrict__ gflag,
                                        int nblk, int gen) {
  __syncthreads();
  const int tid = threadIdx.x;
  if (tid == 0)
    __hip_atomic_store(&slots[blockIdx.x], gen, __ATOMIC_RELAXED, __HIP_MEMORY_SCOPE_AGENT);
  if (blockIdx.x == 0) {
    if (tid < nblk) {
      while (__hip_atomic_load(&slots[tid], __ATOMIC_RELAXED, __HIP_MEMORY_SCOPE_AGENT) < gen) {}
    }
    __syncthreads();
    if (tid == 0)
      __hip_atomic_store(gflag, gen, __ATOMIC_RELAXED, __HIP_MEMORY_SCOPE_AGENT);
  } else {
    if (tid == 0) {
      while (__hip_atomic_load(gflag, __ATOMIC_RELAXED, __HIP_MEMORY_SCOPE_AGENT) < gen)
        __builtin_amdgcn_s_sleep(2);
    }
    __syncthreads();
  }
}

// ---------------------------------------------------------------------------
// Coherent h-slice staging: NR rows x 512 bf16 from global (written with
// agent-scope stores by other XCDs) -> LDS, via L1/L2-bypass dwordx4 loads
// (batched issue, single waitcnt). LDS is XOR-swizzled (byte ^= (row&7)<<4)
// so the MFMA fragment reads (16 lanes @ row-stride 1KB) don't 16-way-conflict.
// ---------------------------------------------------------------------------
template<int NR>
__device__ __forceinline__ void stage_h(short* __restrict__ hs, const short* __restrict__ hsrc) {
  const int tid = threadIdx.x;
  constexpr int NCH = NR * 64 / 256;     // 16B chunks per thread (NR=32 -> 8)
  i32x4 tmp[NCH];
#pragma unroll
  for (int i = 0; i < NCH; ++i) {
    const short* p = hsrc + (size_t)(tid + i * 256) * 8;
    asm volatile("global_load_dwordx4 %0, %1, off sc0 sc1" : "=v"(tmp[i]) : "v"(p));
  }
  asm volatile("s_waitcnt vmcnt(0)" ::: "memory");
  __builtin_amdgcn_sched_barrier(0);
#pragma unroll
  for (int i = 0; i < NCH; ++i) {
    const int c = tid + i * 256;
    const int row = c >> 6;              // 64 chunks per row
    const int wb  = (c & 63) << 4;       // byte within row
    *(i32x4*)((char*)hs + (size_t)row * 1024 + (size_t)(wb ^ ((row & 7) << 4))) = tmp[i];
  }
}

// Swizzled LDS fragment read: row r, element offset kk (multiple of 8).
__device__ __forceinline__ bf16x8 lds_frag(const short* __restrict__ hs, int r, int kk) {
  return *(const bf16x8*)(hs + r * HH + (kk ^ ((r & 7) << 3)));
}

// ---------------------------------------------------------------------------
// Elementwise convert-to-bf16 (Plan A: x -> x_bf). Copies if already bf16.
// ---------------------------------------------------------------------------
__global__ __launch_bounds__(256) void conv_bf16(const void* __restrict__ src,
                                                 __hip_bfloat16* __restrict__ dst,
                                                 const int* __restrict__ flagp,
                                                 size_t n8) {
  const int isbf = flagp[0];
  for (size_t i = (size_t)blockIdx.x * 256 + threadIdx.x; i < n8;
       i += (size_t)gridDim.x * 256) {
    bf16x8 v = ldab(src, i * 8, isbf);
    *(bf16x8*)((short*)dst + i * 8) = v;
  }
}

// ---------------------------------------------------------------------------
// Stash fill (Plans B/C/D): snapshot hazard halves of this pass's b-columns
// from pristine y0 (in out) into bf16 stash.
// ---------------------------------------------------------------------------
__global__ __launch_bounds__(256) void stash_fill(
    const void* __restrict__ out,
    __hip_bfloat16* __restrict__ stashF,
    __hip_bfloat16* __restrict__ stashB,
    const int* __restrict__ flagp,
    int bcount, int pass_off)
{
  const int isbf = flagp[0];
  const size_t total8 = (size_t)2 * 256 * bcount * HH / 8;
  for (size_t i = (size_t)blockIdx.x * 256 + threadIdx.x; i < total8;
       i += (size_t)gridDim.x * 256) {
    const size_t idx = i * 8;
    const int k = (int)(idx & 511);
    const size_t r = idx >> 9;
    const int lb = (int)(r % bcount);
    const size_t rr = r / bcount;
    const int row = (int)(rr & 255);
    const bool isB = rr >= 256;
    const size_t src = ((size_t)(isB ? (256 + row) : row) * BB + pass_off + lb) * 1024 +
                       (isB ? HH : 0) + k;
    bf16x8 v = ldab(out, src, isbf);
    __hip_bfloat16* dst = (isB ? stashB : stashF) + ((size_t)row * bcount + lb) * HH + k;
    *(bf16x8*)(void*)dst = v;
  }
}

// LSTM cell element update (shared by both layers).
#define LSTM_E(JL, BR, CREF, H2) do { \
    float vi = gx[0][JL][ub] + bias_r[0][BR]; \
    float vf = gx[1][JL][ub] + bias_r[1][BR]; \
    float vg = gx[2][JL][ub] + bias_r[2][BR]; \
    float vo = gx[3][JL][ub] + bias_r[3][BR]; \
    const float cold = (CREF) * m; \
    const float c2 = sigf(vf) * cold + sigf(vi) * tanhfast(vg); \
    (H2) = sigf(vo) * tanhfast(c2); \
    (CREF) = c2; \
  } while (0)

// ---------------------------------------------------------------------------
// PERSISTENT LAYER 0. Grid 128 = dir(2) x jtile(32) x bhalf(2), 256 thr.
// Weights one-time in registers; c-state in regs; h exchanged coherently
// (agent atomic stores / sc0sc1 bulk loads -> swizzled LDS). One slot-barrier
// per step; no fences -> weights/x stay L2-resident across all 512 steps.
// Dual-launched per dtype; inactive variant exits on the device flag.
// ---------------------------------------------------------------------------
template<int ISBF, int USE_XBF>
__global__ __launch_bounds__(256, 1) void l0_persist(
    const void* __restrict__ x,
    const __hip_bfloat16* __restrict__ xbf,
    const void* __restrict__ Wih_f, const void* __restrict__ Whh_f, const void* __restrict__ bias_f,
    const void* __restrict__ Wih_b, const void* __restrict__ Whh_b, const void* __restrict__ bias_b,
    __hip_bfloat16* __restrict__ hbuf,   // [2 par][2 dir][64][512] bf16
    const int* __restrict__ lens,
    void* __restrict__ ydst,             // Plan A: y0_bf (bf16); else out (dtype)
    const int* __restrict__ flagp,
    int* __restrict__ slots, int* __restrict__ gflag)
{
  if (flagp[0] != ISBF) return;

  const int bx = blockIdx.x;
  const int d  = bx >> 6;
  const int jt = (bx >> 1) & 31;
  const int bh = bx & 1;

  const void* Wih  = d ? Wih_b  : Wih_f;
  const void* Whh  = d ? Whh_b  : Whh_f;
  const void* bias = d ? bias_b : bias_f;

  const int tid  = threadIdx.x;
  const int lane = tid & 63;
  const int g    = tid >> 6;          // wave = gate (i,f,g,o)
  const int nm   = lane & 15;
  const int kq   = (lane >> 4) * 8;

  // ---- one-time: weights -> registers ----
  bf16x8 wih[16], whh[16];
  {
    const size_t arow = (size_t)(g * HH + jt * 16 + nm) * HH + kq;
#pragma unroll
    for (int ks = 0; ks < 16; ++ks) {
      wih[ks] = ldab(Wih, arow + ks * 32, ISBF);
      whh[ks] = ldab(Whh, arow + ks * 32, ISBF);
    }
  }

  const void* xs = USE_XBF ? (const void*)xbf : x;
  const int   XF = USE_XBF ? 1 : ISBF;
  const int  YBF = USE_XBF ? 1 : ISBF;

  // update-phase statics
  const int ub  = tid >> 3;              // local batch 0..31
  const int jq  = (tid & 7) * 2;         // j pair base
  const int b_g = bh * 32 + ub;
  const int j_g = jt * 16 + jq;
  const int len = lens[b_g];
  float bias_r[4][2];
#pragma unroll
  for (int q = 0; q < 4; ++q) {
    bias_r[q][0] = ldsc(bias, q * HH + j_g, ISBF);
    bias_r[q][1] = ldsc(bias, q * HH + j_g + 1, ISBF);
  }
  float c0 = 0.f, c1 = 0.f;

  __shared__ float gx[4][16][33];
  __shared__ __align__(16) short hs[32 * HH];

  const size_t hrow0 = (size_t)(bh * 32) * HH;   // within dir slice

  for (int s = 0; s < TT; ++s) {
    const int t_eff = d ? (TT - 1 - s) : s;

    // stage this block's 32 h rows (dir d, parity s&1), coherently
    const short* hsrc = (const short*)hbuf + ((size_t)(s & 1) * 2 + d) * (size_t)(BB * HH) + hrow0;
    stage_h<32>(hs, hsrc);
    __syncthreads();

    f32x4 acc0 = {0.f, 0.f, 0.f, 0.f};
    f32x4 acc1 = {0.f, 0.f, 0.f, 0.f};
    const size_t xo0 = ((size_t)t_eff * BB + bh * 32 + nm) * HH + kq;
    const size_t xo1 = xo0 + (size_t)16 * HH;
#pragma unroll 8
    for (int ks = 0; ks < 16; ++ks) {
      acc0 = MFMA(wih[ks], ldab(xs, xo0 + ks * 32, XF), acc0, 0, 0, 0);
      acc1 = MFMA(wih[ks], ldab(xs, xo1 + ks * 32, XF), acc1, 0, 0, 0);
    }
#pragma unroll
    for (int ks = 0; ks < 16; ++ks) {
      const int kk = kq + ks * 32;
      acc0 = MFMA(whh[ks], lds_frag(hs, nm, kk), acc0, 0, 0, 0);
      acc1 = MFMA(whh[ks], lds_frag(hs, nm + 16, kk), acc1, 0, 0, 0);
    }
    {
      const int quad = lane >> 4;
#pragma unroll
      for (int r = 0; r < 4; ++r) {
        gx[g][quad * 4 + r][nm]      = acc0[r];
        gx[g][quad * 4 + r][16 + nm] = acc1[r];
      }
    }
    __syncthreads();

    // ---- fused update ----
    {
      const float m = (t_eff < len) ? 1.0f : 0.0f;
      const int tn = d ? (t_eff - 1) : (t_eff + 1);
      const float mn = (tn >= 0 && tn < len) ? 1.0f : 0.0f;
      float hva, hvb;
      LSTM_E(jq,     0, c0, hva);
      LSTM_E(jq + 1, 1, c1, hvb);
      // h: packed pair, write-through agent store (pre-masked w/ next mask)
      unsigned int hp = (unsigned int)(unsigned short)f2bf(hva * mn) |
                        ((unsigned int)(unsigned short)f2bf(hvb * mn) << 16);
      unsigned int* hnxt = (unsigned int*)((short*)hbuf +
          ((size_t)((s + 1) & 1) * 2 + d) * (size_t)(BB * HH) + (size_t)b_g * HH + j_g);
      __hip_atomic_store(hnxt, hp, __ATOMIC_RELAXED, __HIP_MEMORY_SCOPE_AGENT);
      // y: normal store (consumed only after this dispatch ends)
      const size_t yb = ((size_t)t_eff * BB + b_g) * 1024 + (size_t)d * HH + j_g;
      if (YBF) {
        unsigned int yp = (unsigned int)(unsigned short)f2bf(hva * m) |
                          ((unsigned int)(unsigned short)f2bf(hvb * m) << 16);
        *(unsigned int*)((short*)ydst + yb) = yp;
      } else {
        *(float2*)((float*)ydst + yb) = make_float2(hva * m, hvb * m);
      }
    }
    if (s != TT - 1) slotbar(slots, gflag, 128, s + 1);
  }
}

// ---------------------------------------------------------------------------
// PERSISTENT LAYER 1. Grid 64*nbh = dir(2) x jtile(32) x bhalf(nbh).
// USE_Y0 (Plan A): reads pristine bf16 y0 -> out never read -> 1 barrier/step.
// Else: in-place over out + stash; mid-step barrier orders all pristine out
// reads before any out write (values are single-read-before-write, so no
// coherent out access needed). h exchanged coherently as in layer 0.
// ---------------------------------------------------------------------------
template<int ISBF, int USE_Y0>
__global__ __launch_bounds__(256, 1) void l1_persist(
    const void* __restrict__ Wih_f, const void* __restrict__ Whh_f, const void* __restrict__ bias_f,
    const void* __restrict__ Wih_b, const void* __restrict__ Whh_b, const void* __restrict__ bias_b,
    const void* __restrict__ ysrc,   // out (in-place) or y0_bf (Plan A)
    const __hip_bfloat16* __restrict__ stashF,
    const __hip_bfloat16* __restrict__ stashB,
    __hip_bfloat16* __restrict__ hbuf,
    const int* __restrict__ lens,
    void* __restrict__ out,
    const int* __restrict__ flagp,
    int* __restrict__ slots, int* __restrict__ gflag,
    int pass_off, int nb, int nbh, int bcount)
{
  if (flagp[0] != ISBF) return;

  const int bx = blockIdx.x;
  const int nblk = 64 * nbh;
  const int d   = bx / (32 * nbh);
  const int rem = bx % (32 * nbh);
  const int jt  = rem / nbh;
  const int bh  = rem % nbh;

  const void* Wih  = d ? Wih_b  : Wih_f;
  const void* Whh  = d ? Whh_b  : Whh_f;
  const void* bias = d ? bias_b : bias_f;

  const int tid  = threadIdx.x;
  const int lane = tid & 63;
  const int g    = tid >> 6;
  const int nm   = lane & 15;
  const int kq   = (lane >> 4) * 8;

  // ---- one-time: weights -> registers ----
  bf16x8 wih[32], whh[16];
  {
    const size_t arow_ih = (size_t)(g * HH + jt * 16 + nm) * 1024 + kq;
    const size_t arow_hh = (size_t)(g * HH + jt * 16 + nm) * HH + kq;
#pragma unroll
    for (int ks = 0; ks < 32; ++ks) wih[ks] = ldab(Wih, arow_ih + ks * 32, ISBF);
#pragma unroll
    for (int ks = 0; ks < 16; ++ks) whh[ks] = ldab(Whh, arow_hh + ks * 32, ISBF);
  }

  const bool NBT2 = (nb == 32);
  const int lb0 = bh * nb + nm;          // local batch row
  const int SRCF = USE_Y0 ? 1 : ISBF;

  const int ub  = NBT2 ? (tid >> 3) : (tid >> 4);
  const int jq  = NBT2 ? ((tid & 7) * 2) : (tid & 15);
  const int b_g = pass_off + bh * nb + ub;
  const int j_g = jt * 16 + jq;
  const int len = lens[b_g];
  float bias_r[4][2];
#pragma unroll
  for (int q = 0; q < 4; ++q) {
    bias_r[q][0] = ldsc(bias, q * HH + j_g, ISBF);
    bias_r[q][1] = NBT2 ? ldsc(bias, q * HH + j_g + 1, ISBF) : 0.f;
  }
  float c0 = 0.f, c1 = 0.f;

  __shared__ float gx[4][16][33];
  __shared__ __align__(16) short hs[32 * HH];

  const size_t hrow0 = (size_t)(pass_off + bh * nb) * HH;  // within dir slice

  for (int s = 0; s < TT; ++s) {
    const int t_eff = d ? (TT - 1 - s) : s;

    const short* hsrc = (const short*)hbuf + ((size_t)(s & 1) * 2 + d) * (size_t)(BB * HH) + hrow0;
    if (NBT2) stage_h<32>(hs, hsrc); else stage_h<16>(hs, hsrc);
    __syncthreads();

    // resolve per-half input sources (wave-uniform)
    const void* pl; size_t ol; int stl; int fl;
    const void* ph; size_t oh; int sth; int fh;
    if (d == 0) {
      pl = ysrc; ol = ((size_t)t_eff * BB + pass_off) * 1024; stl = 1024; fl = SRCF;
      if (USE_Y0 || s < 256) { ph = ysrc; oh = ol + HH; sth = 1024; fh = SRCF; }
      else { ph = stashB; oh = (size_t)(s - 256) * bcount * HH; sth = HH; fh = 1; }
    } else {
      ph = ysrc; oh = ((size_t)t_eff * BB + pass_off) * 1024 + HH; sth = 1024; fh = SRCF;
      if (USE_Y0 || s < 256) { pl = ysrc; ol = ((size_t)t_eff * BB + pass_off) * 1024; stl = 1024; fl = SRCF; }
      else { pl = stashF; ol = (size_t)t_eff * bcount * HH; stl = HH; fl = 1; }
    }

    f32x4 acc0 = {0.f, 0.f, 0.f, 0.f};
    f32x4 acc1 = {0.f, 0.f, 0.f, 0.f};
#pragma unroll 8
    for (int ks = 0; ks < 16; ++ks) {
      const size_t krel = (size_t)ks * 32 + kq;
      acc0 = MFMA(wih[ks], ldab(pl, ol + (size_t)lb0 * stl + krel, fl), acc0, 0, 0, 0);
      if (NBT2)
        acc1 = MFMA(wih[ks], ldab(pl, ol + (size_t)(lb0 + 16) * stl + krel, fl), acc1, 0, 0, 0);
    }
#pragma unroll 8
    for (int ks = 0; ks < 16; ++ks) {
      const size_t krel = (size_t)ks * 32 + kq;
      acc0 = MFMA(wih[16 + ks], ldab(ph, oh + (size_t)lb0 * sth + krel, fh), acc0, 0, 0, 0);
      if (NBT2)
        acc1 = MFMA(wih[16 + ks], ldab(ph, oh + (size_t)(lb0 + 16) * sth + krel, fh), acc1, 0, 0, 0);
    }
#pragma unroll
    for (int ks = 0; ks < 16; ++ks) {
      const int kk = kq + ks * 32;
      acc0 = MFMA(whh[ks], lds_frag(hs, nm, kk), acc0, 0, 0, 0);
      if (NBT2) acc1 = MFMA(whh[ks], lds_frag(hs, nm + 16, kk), acc1, 0, 0, 0);
    }
    {
      const int quad = lane >> 4;
#pragma unroll
      for (int r = 0; r < 4; ++r) {
        gx[g][quad * 4 + r][nm] = acc0[r];
        if (NBT2) gx[g][quad * 4 + r][16 + nm] = acc1[r];
      }
    }
    // In-place: all pristine out reads grid-wide before any out write.
    if (!USE_Y0) slotbar(slots, gflag, nblk, 2 * s + 1);
    else __syncthreads();

    {
      const float m = (t_eff < len) ? 1.0f : 0.0f;
      const int tn = d ? (t_eff - 1) : (t_eff + 1);
      const float mn = (tn >= 0 && tn < len) ? 1.0f : 0.0f;
      const size_t hoff = ((size_t)((s + 1) & 1) * 2 + d) * (size_t)(BB * HH) +
                          (size_t)b_g * HH + j_g;
      const size_t yb = ((size_t)t_eff * BB + b_g) * 1024 + (size_t)d * HH + j_g;
      if (NBT2) {
        float hva, hvb;
        LSTM_E(jq,     0, c0, hva);
        LSTM_E(jq + 1, 1, c1, hvb);
        unsigned int hp = (unsigned int)(unsigned short)f2bf(hva * mn) |
                          ((unsigned int)(unsigned short)f2bf(hvb * mn) << 16);
        __hip_atomic_store((unsigned int*)((short*)hbuf + hoff), hp,
                           __ATOMIC_RELAXED, __HIP_MEMORY_SCOPE_AGENT);
        if (ISBF) {
          unsigned int yp = (unsigned int)(unsigned short)f2bf(hva * m) |
                            ((unsigned int)(unsigned short)f2bf(hvb * m) << 16);
          *(unsigned int*)((short*)out + yb) = yp;
        } else {
          *(float2*)((float*)out + yb) = make_float2(hva * m, hvb * m);
        }
      } else {
        float hv;
        LSTM_E(jq, 0, c0, hv);
        unsigned short hu = (unsigned short)f2bf(hv * mn);
        int other = __shfl_xor((int)hu, 1);
        if ((tid & 1) == 0) {
          unsigned int hp = (unsigned int)hu | ((unsigned int)(unsigned short)other << 16);
          __hip_atomic_store((unsigned int*)((short*)hbuf + hoff), hp,
                             __ATOMIC_RELAXED, __HIP_MEMORY_SCOPE_AGENT);
        }
        if (ISBF) ((__hip_bfloat16*)out)[yb] = __float2bfloat16(hv * m);
        else      ((float*)out)[yb] = hv * m;
      }
    }
    if (s != TT - 1) slotbar(slots, gflag, nblk, USE_Y0 ? (s + 1) : (2 * s + 2));
  }
}

// ---------------------------------------------------------------------------
extern "C" void kernel_launch(void* const* d_in, const int* in_sizes, int n_in,
                              void* d_out, int out_size, void* d_ws, size_t ws_size,
                              hipStream_t stream) {
  (void)in_sizes; (void)n_in; (void)out_size;
  const void* x     = d_in[0];
  const int*  lens  = (const int*)d_in[1];
  const void* fWih0 = d_in[2];
  const void* fWhh0 = d_in[3];
  const void* fb0   = d_in[4];
  const void* bWih0 = d_in[5];
  const void* bWhh0 = d_in[6];
  const void* bb0   = d_in[7];
  const void* fWih1 = d_in[8];
  const void* fWhh1 = d_in[9];
  const void* fb1   = d_in[10];
  const void* bWih1 = d_in[11];
  const void* bWhh1 = d_in[12];
  const void* bb1   = d_in[13];
  void* out = d_out;

  // --- ws layout: [flag][slots 512B @512][gflag @1024][hb @2048][plan region] ---
  char* w = (char*)d_ws;
  int* flagp = (int*)w;
  int* slots = (int*)(w + 512);
  int* gflag = (int*)(w + 1024);
  __hip_bfloat16* hb = (__hip_bfloat16*)(w + 2048);
  const size_t HBYTES = (size_t)2 * 2 * BB * HH * sizeof(__hip_bfloat16); // 256 KiB
  char* dyn = w + 2048 + HBYTES;
  const size_t avail = (ws_size > 2048 + HBYTES) ? (ws_size - 2048 - HBYTES) : 0;

  const size_t XBF = (size_t)TT * BB * HH * 2;     // 32 MB bf16 x
  const size_t Y0B = (size_t)TT * BB * 1024 * 2;   // 64 MB bf16 y0

  sniff<<<1, 256, 0, stream>>>((const unsigned int*)x, flagp);

  if (avail >= XBF + Y0B) {
    // ---- Plan A: separate bf16 y0; out never read in l1 -> 1 barrier/step ----
    __hip_bfloat16* xbf = (__hip_bfloat16*)dyn;
    __hip_bfloat16* y0  = (__hip_bfloat16*)(dyn + XBF);
    conv_bf16<<<2048, 256, 0, stream>>>(x, xbf, flagp, (size_t)TT * BB * HH / 8);
    hipMemsetAsync(hb, 0, HBYTES, stream);
    hipMemsetAsync(w + 512, 0, 1024, stream);
    l0_persist<0, 1><<<128, 256, 0, stream>>>(x, xbf, fWih0, fWhh0, fb0, bWih0, bWhh0, bb0,
                                              hb, lens, y0, flagp, slots, gflag);
    l0_persist<1, 1><<<128, 256, 0, stream>>>(x, xbf, fWih0, fWhh0, fb0, bWih0, bWhh0, bb0,
                                              hb, lens, y0, flagp, slots, gflag);
    hipMemsetAsync(hb, 0, HBYTES, stream);
    hipMemsetAsync(w + 512, 0, 1024, stream);
    l1_persist<0, 1><<<128, 256, 0, stream>>>(fWih1, fWhh1, fb1, bWih1, bWhh1, bb1,
                                              y0, nullptr, nullptr, hb, lens, out,
                                              flagp, slots, gflag, 0, 32, 2, 64);
    l1_persist<1, 1><<<128, 256, 0, stream>>>(fWih1, fWhh1, fb1, bWih1, bWhh1, bb1,
                                              y0, nullptr, nullptr, hb, lens, out,
                                              flagp, slots, gflag, 0, 32, 2, 64);
  } else {
    // ---- Plans B/C/D: in-place out + bf16 stash of hazard halves ----
    const int bcount = (avail >= (size_t)64 * 524288) ? 64 :
                       (avail >= (size_t)32 * 524288) ? 32 : 16;
    const int nb  = (bcount == 64) ? 32 : 16;
    const int nbh = (bcount == 16) ? 1 : 2;
    __hip_bfloat16* stashF = (__hip_bfloat16*)dyn;
    __hip_bfloat16* stashB = stashF + (size_t)256 * bcount * HH;

    hipMemsetAsync(hb, 0, HBYTES, stream);
    hipMemsetAsync(w + 512, 0, 1024, stream);
    l0_persist<0, 0><<<128, 256, 0, stream>>>(x, nullptr, fWih0, fWhh0, fb0, bWih0, bWhh0, bb0,
                                              hb, lens, out, flagp, slots, gflag);
    l0_persist<1, 0><<<128, 256, 0, stream>>>(x, nullptr, fWih0, fWhh0, fb0, bWih0, bWhh0, bb0,
                                              hb, lens, out, flagp, slots, gflag);
    const int P = 64 / bcount;
    for (int p = 0; p < P; ++p) {
      stash_fill<<<1024, 256, 0, stream>>>(out, stashF, stashB, flagp, bcount, p * bcount);
      hipMemsetAsync(hb, 0, HBYTES, stream);
      hipMemsetAsync(w + 512, 0, 1024, stream);
      l1_persist<0, 0><<<64 * nbh, 256, 0, stream>>>(fWih1, fWhh1, fb1, bWih1, bWhh1, bb1,
                                                     out, stashF, stashB, hb, lens, out,
                                                     flagp, slots, gflag, p * bcount, nb, nbh, bcount);
      l1_persist<1, 0><<<64 * nbh, 256, 0, stream>>>(fWih1, fWhh1, fb1, bWih1, bWhh1, bb1,
                                                     out, stashF, stashB, hb, lens, out,
                                                     flagp, slots, gflag, p * bcount, nb, nbh, bcount);
    }
  }
}

// Round 3
// 12255.219 us; speedup vs baseline: 2.8399x; 1.2086x over previous
//
#include <hip/hip_runtime.h>
#include <hip/hip_bf16.h>
#include <cstddef>
#include <cstdint>

// Problem dims (fixed): T=512, B=64, D=H=512, gates = 4*H = 2048
#define TT 512
#define BB 64
#define HH 512

typedef __attribute__((ext_vector_type(8))) short bf16x8;   // 8 bf16 = 4 VGPRs
typedef __attribute__((ext_vector_type(4))) float f32x4;    // MFMA C/D
typedef __attribute__((ext_vector_type(4))) int   i32x4;    // 16B staging reg

__device__ __forceinline__ float sigf(float x) { return 1.0f / (1.0f + __expf(-x)); }
__device__ __forceinline__ float tanhfast(float x) { return 2.0f / (1.0f + __expf(-2.0f * x)) - 1.0f; }

// fp32 -> bf16 (round-nearest-even), as raw short
__device__ __forceinline__ short f2bf(float x) {
  uint32_t u = __float_as_uint(x);
  u += 0x7FFFu + ((u >> 16) & 1u);
  return (short)(u >> 16);
}

// MFMA with weight operand PINNED to AGPRs ("a" constraint). s_nop 1 covers
// the VALU-write -> MFMA-srcB hazard (fp32->bf16 convert feeding B) that the
// compiler can't see inside asm. Accumulator chaining (C==D) is hazard-free.
__device__ __forceinline__ f32x4 mfma_a(bf16x8 w, bf16x8 b, f32x4 acc) {
  asm("s_nop 1\n\tv_mfma_f32_16x16x32_bf16 %0, %1, %2, %0"
      : "+v"(acc) : "a"(w), "v"(b));
  return acc;
}
// Data-dependent hazard fence: orders after the last mfma_a (reads accs) and
// before any VALU read of accs (writes accs); 24 cycles covers MFMA->VALU.
__device__ __forceinline__ void mfma_fence(f32x4& a0, f32x4& a1) {
  asm volatile("s_nop 7\n\ts_nop 7\n\ts_nop 7" : "+v"(a0), "+v"(a1));
}

// Adaptive 8-element fragment load (element-indexed). isbf: 1 = bf16, 0 = fp32.
__device__ __forceinline__ bf16x8 ldab(const void* base, size_t e, int isbf) {
  if (isbf) return *(const bf16x8*)((const short*)base + e);
  const float* f = (const float*)base + e;
  float4 a = *(const float4*)f;
  float4 b = *(const float4*)(f + 4);
  bf16x8 r;
  r[0] = f2bf(a.x); r[1] = f2bf(a.y); r[2] = f2bf(a.z); r[3] = f2bf(a.w);
  r[4] = f2bf(b.x); r[5] = f2bf(b.y); r[6] = f2bf(b.z); r[7] = f2bf(b.w);
  return r;
}

__device__ __forceinline__ float ldsc(const void* base, size_t e, int isbf) {
  if (isbf) return (float)((const __hip_bfloat16*)base)[e];
  return ((const float*)base)[e];
}

// ---------------------------------------------------------------------------
// Dtype sniffer (proven): majority-vote on bf16-pair exponent bits.
// ---------------------------------------------------------------------------
__global__ __launch_bounds__(256) void sniff(const unsigned int* __restrict__ x,
                                             int* __restrict__ flag) {
  __shared__ int cnt[256];
  int c = 0;
#pragma unroll
  for (int i = 0; i < 16; ++i) {
    unsigned w = x[threadIdx.x * 16 + i];
    unsigned e = (w >> 7) & 0xFFu;
    c += (e >= 110u && e <= 140u) ? 1 : 0;
  }
  cnt[threadIdx.x] = c;
  __syncthreads();
  for (int s = 128; s > 0; s >>= 1) {
    if ((int)threadIdx.x < s) cnt[threadIdx.x] += cnt[threadIdx.x + s];
    __syncthreads();
  }
  if (threadIdx.x == 0) flag[0] = (cnt[0] > 2048) ? 1 : 0;
}

// ---------------------------------------------------------------------------
// De-contended slot barrier. slots[i*16] (64B apart): arrival gen per block.
// rflag[i*16] (64B apart): per-block release word, fanned out by block 0.
// No RMWs, no same-line polling storms, no cache-invalidating fences.
// Entry __syncthreads drains each thread's stores (incl. agent h stores)
// before arrival is signaled; release ordered after all arrivals.
// ---------------------------------------------------------------------------
__device__ __forceinline__ void slotbar(int* __restrict__ slots, int nblk, int gen) {
  __syncthreads();
  const int tid = threadIdx.x;
  int* rflag = slots + 2048;           // +8KB
  if (blockIdx.x == 0) {
    if (tid > 0 && tid < nblk) {
      while (__hip_atomic_load(&slots[tid * 16], __ATOMIC_RELAXED, __HIP_MEMORY_SCOPE_AGENT) < gen)
        __builtin_amdgcn_s_sleep(1);
    }
    __syncthreads();
    if (tid < nblk)
      __hip_atomic_store(&rflag[tid * 16], gen, __ATOMIC_RELAXED, __HIP_MEMORY_SCOPE_AGENT);
  } else {
    if (tid == 0) {
      __hip_atomic_store(&slots[blockIdx.x * 16], gen, __ATOMIC_RELAXED, __HIP_MEMORY_SCOPE_AGENT);
      while (__hip_atomic_load(&rflag[blockIdx.x * 16], __ATOMIC_RELAXED, __HIP_MEMORY_SCOPE_AGENT) < gen)
        __builtin_amdgcn_s_sleep(1);
    }
    __syncthreads();
  }
}

// ---------------------------------------------------------------------------
// Split coherent h-slice staging: issue (L1/L2-bypass loads into regs) early,
// commit (waitcnt + swizzled LDS write) after the Wih MFMA section, hiding
// the MALL round-trip under compute. LDS XOR-swizzled (byte ^= (row&7)<<4).
// ---------------------------------------------------------------------------
template<int NR>
struct HStage { i32x4 tmp[NR * 64 / 256]; };

template<int NR>
__device__ __forceinline__ void stage_issue(HStage<NR>& st, const short* __restrict__ hsrc) {
  const int tid = threadIdx.x;
#pragma unroll
  for (int i = 0; i < NR * 64 / 256; ++i) {
    const short* p = hsrc + (size_t)(tid + i * 256) * 8;
    asm volatile("global_load_dwordx4 %0, %1, off sc0 sc1" : "=v"(st.tmp[i]) : "v"(p));
  }
}

template<int NR>
__device__ __forceinline__ void stage_commit(HStage<NR>& st, short* __restrict__ hs) {
  const int tid = threadIdx.x;
  asm volatile("s_waitcnt vmcnt(0)" ::: "memory");
  __builtin_amdgcn_sched_barrier(0);
#pragma unroll
  for (int i = 0; i < NR * 64 / 256; ++i) {
    const int c = tid + i * 256;
    const int row = c >> 6;              // 64 chunks per row
    const int wb  = (c & 63) << 4;       // byte within row
    *(i32x4*)((char*)hs + (size_t)row * 1024 + (size_t)(wb ^ ((row & 7) << 4))) = st.tmp[i];
  }
}

// Swizzled LDS fragment read: row r, element offset kk (multiple of 8).
__device__ __forceinline__ bf16x8 lds_frag(const short* __restrict__ hs, int r, int kk) {
  return *(const bf16x8*)(hs + r * HH + (kk ^ ((r & 7) << 3)));
}

// ---------------------------------------------------------------------------
// Elementwise convert-to-bf16 (Plan A: x -> x_bf). Copies if already bf16.
// ---------------------------------------------------------------------------
__global__ __launch_bounds__(256) void conv_bf16(const void* __restrict__ src,
                                                 __hip_bfloat16* __restrict__ dst,
                                                 const int* __restrict__ flagp,
                                                 size_t n8) {
  const int isbf = flagp[0];
  for (size_t i = (size_t)blockIdx.x * 256 + threadIdx.x; i < n8;
       i += (size_t)gridDim.x * 256) {
    bf16x8 v = ldab(src, i * 8, isbf);
    *(bf16x8*)((short*)dst + i * 8) = v;
  }
}

// ---------------------------------------------------------------------------
// Stash fill (Plans B/C/D): snapshot hazard halves of this pass's b-columns
// from pristine y0 (in out) into bf16 stash.
// ---------------------------------------------------------------------------
__global__ __launch_bounds__(256) void stash_fill(
    const void* __restrict__ out,
    __hip_bfloat16* __restrict__ stashF,
    __hip_bfloat16* __restrict__ stashB,
    const int* __restrict__ flagp,
    int bcount, int pass_off)
{
  const int isbf = flagp[0];
  const size_t total8 = (size_t)2 * 256 * bcount * HH / 8;
  for (size_t i = (size_t)blockIdx.x * 256 + threadIdx.x; i < total8;
       i += (size_t)gridDim.x * 256) {
    const size_t idx = i * 8;
    const int k = (int)(idx & 511);
    const size_t r = idx >> 9;
    const int lb = (int)(r % bcount);
    const size_t rr = r / bcount;
    const int row = (int)(rr & 255);
    const bool isB = rr >= 256;
    const size_t src = ((size_t)(isB ? (256 + row) : row) * BB + pass_off + lb) * 1024 +
                       (isB ? HH : 0) + k;
    bf16x8 v = ldab(out, src, isbf);
    __hip_bfloat16* dst = (isB ? stashB : stashF) + ((size_t)row * bcount + lb) * HH + k;
    *(bf16x8*)(void*)dst = v;
  }
}

// LSTM cell element update (shared by both layers).
#define LSTM_E(JL, BR, CREF, H2) do { \
    float vi = gx[0][JL][ub] + bias_r[0][BR]; \
    float vf = gx[1][JL][ub] + bias_r[1][BR]; \
    float vg = gx[2][JL][ub] + bias_r[2][BR]; \
    float vo = gx[3][JL][ub] + bias_r[3][BR]; \
    const float cold = (CREF) * m; \
    const float c2 = sigf(vf) * cold + sigf(vi) * tanhfast(vg); \
    (H2) = sigf(vo) * tanhfast(c2); \
    (CREF) = c2; \
  } while (0)

// ---------------------------------------------------------------------------
// PERSISTENT LAYER 0. Grid 128 = dir(2) x jtile(32) x bhalf(2), 256 thr.
// Weights one-time in AGPRs (asm-pinned); c-state in regs; h exchanged
// coherently (agent stores / sc0sc1 staged loads -> swizzled LDS).
// One slot-barrier per step.
// ---------------------------------------------------------------------------
template<int ISBF, int USE_XBF>
__global__ __launch_bounds__(256, 1) void l0_persist(
    const void* __restrict__ x,
    const __hip_bfloat16* __restrict__ xbf,
    const void* __restrict__ Wih_f, const void* __restrict__ Whh_f, const void* __restrict__ bias_f,
    const void* __restrict__ Wih_b, const void* __restrict__ Whh_b, const void* __restrict__ bias_b,
    __hip_bfloat16* __restrict__ hbuf,   // [2 par][2 dir][64][512] bf16
    const int* __restrict__ lens,
    void* __restrict__ ydst,             // Plan A: y0_bf (bf16); else out (dtype)
    const int* __restrict__ flagp,
    int* __restrict__ slots)
{
  if (flagp[0] != ISBF) return;

  const int bx = blockIdx.x;
  const int d  = bx >> 6;
  const int jt = (bx >> 1) & 31;
  const int bh = bx & 1;

  const void* Wih  = d ? Wih_b  : Wih_f;
  const void* Whh  = d ? Whh_b  : Whh_f;
  const void* bias = d ? bias_b : bias_f;

  const int tid  = threadIdx.x;
  const int lane = tid & 63;
  const int g    = tid >> 6;          // wave = gate (i,f,g,o)
  const int nm   = lane & 15;
  const int kq   = (lane >> 4) * 8;

  // ---- one-time: weights -> registers (AGPR-resident via asm "a" use) ----
  bf16x8 wih[16], whh[16];
  {
    const size_t arow = (size_t)(g * HH + jt * 16 + nm) * HH + kq;
#pragma unroll
    for (int ks = 0; ks < 16; ++ks) {
      wih[ks] = ldab(Wih, arow + ks * 32, ISBF);
      whh[ks] = ldab(Whh, arow + ks * 32, ISBF);
    }
  }

  const void* xs = USE_XBF ? (const void*)xbf : x;
  const int   XF = USE_XBF ? 1 : ISBF;
  const int  YBF = USE_XBF ? 1 : ISBF;

  // update-phase statics
  const int ub  = tid >> 3;              // local batch 0..31
  const int jq  = (tid & 7) * 2;         // j pair base
  const int b_g = bh * 32 + ub;
  const int j_g = jt * 16 + jq;
  const int len = lens[b_g];
  float bias_r[4][2];
#pragma unroll
  for (int q = 0; q < 4; ++q) {
    bias_r[q][0] = ldsc(bias, q * HH + j_g, ISBF);
    bias_r[q][1] = ldsc(bias, q * HH + j_g + 1, ISBF);
  }
  float c0 = 0.f, c1 = 0.f;

  __shared__ float gx[4][16][33];
  __shared__ __align__(16) short hs[32 * HH];

  const size_t hrow0 = (size_t)(bh * 32) * HH;   // within dir slice

  for (int s = 0; s < TT; ++s) {
    const int t_eff = d ? (TT - 1 - s) : s;

    // issue h staging early; commit after the Wih section
    HStage<32> st;
    const short* hsrc = (const short*)hbuf + ((size_t)(s & 1) * 2 + d) * (size_t)(BB * HH) + hrow0;
    stage_issue<32>(st, hsrc);

    f32x4 acc0 = {0.f, 0.f, 0.f, 0.f};
    f32x4 acc1 = {0.f, 0.f, 0.f, 0.f};
    const size_t xo0 = ((size_t)t_eff * BB + bh * 32 + nm) * HH + kq;
    const size_t xo1 = xo0 + (size_t)16 * HH;
#pragma unroll
    for (int ks = 0; ks < 16; ++ks) {
      acc0 = mfma_a(wih[ks], ldab(xs, xo0 + ks * 32, XF), acc0);
      acc1 = mfma_a(wih[ks], ldab(xs, xo1 + ks * 32, XF), acc1);
    }
    stage_commit<32>(st, hs);
    __syncthreads();
#pragma unroll
    for (int ks = 0; ks < 16; ++ks) {
      const int kk = kq + ks * 32;
      acc0 = mfma_a(whh[ks], lds_frag(hs, nm, kk), acc0);
      acc1 = mfma_a(whh[ks], lds_frag(hs, nm + 16, kk), acc1);
    }
    mfma_fence(acc0, acc1);
    {
      const int quad = lane >> 4;
#pragma unroll
      for (int r = 0; r < 4; ++r) {
        gx[g][quad * 4 + r][nm]      = acc0[r];
        gx[g][quad * 4 + r][16 + nm] = acc1[r];
      }
    }
    __syncthreads();

    // ---- fused update ----
    {
      const float m = (t_eff < len) ? 1.0f : 0.0f;
      const int tn = d ? (t_eff - 1) : (t_eff + 1);
      const float mn = (tn >= 0 && tn < len) ? 1.0f : 0.0f;
      float hva, hvb;
      LSTM_E(jq,     0, c0, hva);
      LSTM_E(jq + 1, 1, c1, hvb);
      unsigned int hp = (unsigned int)(unsigned short)f2bf(hva * mn) |
                        ((unsigned int)(unsigned short)f2bf(hvb * mn) << 16);
      unsigned int* hnxt = (unsigned int*)((short*)hbuf +
          ((size_t)((s + 1) & 1) * 2 + d) * (size_t)(BB * HH) + (size_t)b_g * HH + j_g);
      __hip_atomic_store(hnxt, hp, __ATOMIC_RELAXED, __HIP_MEMORY_SCOPE_AGENT);
      const size_t yb = ((size_t)t_eff * BB + b_g) * 1024 + (size_t)d * HH + j_g;
      if (YBF) {
        unsigned int yp = (unsigned int)(unsigned short)f2bf(hva * m) |
                          ((unsigned int)(unsigned short)f2bf(hvb * m) << 16);
        *(unsigned int*)((short*)ydst + yb) = yp;
      } else {
        *(float2*)((float*)ydst + yb) = make_float2(hva * m, hvb * m);
      }
    }
    if (s != TT - 1) slotbar(slots, 128, s + 1);
  }
}

// ---------------------------------------------------------------------------
// PERSISTENT LAYER 1. Grid 64*nbh = dir(2) x jtile(32) x bhalf(nbh).
// Weights one-time in AGPRs (192: wih[32]+whh[16]). USE_Y0 (Plan A): reads
// pristine bf16 y0 -> 1 barrier/step. Else: in-place over out + stash with
// mid-step barrier ordering pristine reads before writes.
// ---------------------------------------------------------------------------
template<int ISBF, int USE_Y0>
__global__ __launch_bounds__(256, 1) void l1_persist(
    const void* __restrict__ Wih_f, const void* __restrict__ Whh_f, const void* __restrict__ bias_f,
    const void* __restrict__ Wih_b, const void* __restrict__ Whh_b, const void* __restrict__ bias_b,
    const void* __restrict__ ysrc,   // out (in-place) or y0_bf (Plan A)
    const __hip_bfloat16* __restrict__ stashF,
    const __hip_bfloat16* __restrict__ stashB,
    __hip_bfloat16* __restrict__ hbuf,
    const int* __restrict__ lens,
    void* __restrict__ out,
    const int* __restrict__ flagp,
    int* __restrict__ slots,
    int pass_off, int nb, int nbh, int bcount)
{
  if (flagp[0] != ISBF) return;

  const int bx = blockIdx.x;
  const int nblk = 64 * nbh;
  const int d   = bx / (32 * nbh);
  const int rem = bx % (32 * nbh);
  const int jt  = rem / nbh;
  const int bh  = rem % nbh;

  const void* Wih  = d ? Wih_b  : Wih_f;
  const void* Whh  = d ? Whh_b  : Whh_f;
  const void* bias = d ? bias_b : bias_f;

  const int tid  = threadIdx.x;
  const int lane = tid & 63;
  const int g    = tid >> 6;
  const int nm   = lane & 15;
  const int kq   = (lane >> 4) * 8;

  // ---- one-time: weights -> registers (AGPR-resident via asm "a" use) ----
  bf16x8 wih[32], whh[16];
  {
    const size_t arow_ih = (size_t)(g * HH + jt * 16 + nm) * 1024 + kq;
    const size_t arow_hh = (size_t)(g * HH + jt * 16 + nm) * HH + kq;
#pragma unroll
    for (int ks = 0; ks < 32; ++ks) wih[ks] = ldab(Wih, arow_ih + ks * 32, ISBF);
#pragma unroll
    for (int ks = 0; ks < 16; ++ks) whh[ks] = ldab(Whh, arow_hh + ks * 32, ISBF);
  }

  const bool NBT2 = (nb == 32);
  const int lb0 = bh * nb + nm;          // local batch row
  const int SRCF = USE_Y0 ? 1 : ISBF;

  const int ub  = NBT2 ? (tid >> 3) : (tid >> 4);
  const int jq  = NBT2 ? ((tid & 7) * 2) : (tid & 15);
  const int b_g = pass_off + bh * nb + ub;
  const int j_g = jt * 16 + jq;
  const int len = lens[b_g];
  float bias_r[4][2];
#pragma unroll
  for (int q = 0; q < 4; ++q) {
    bias_r[q][0] = ldsc(bias, q * HH + j_g, ISBF);
    bias_r[q][1] = NBT2 ? ldsc(bias, q * HH + j_g + 1, ISBF) : 0.f;
  }
  float c0 = 0.f, c1 = 0.f;

  __shared__ float gx[4][16][33];
  __shared__ __align__(16) short hs[32 * HH];

  const size_t hrow0 = (size_t)(pass_off + bh * nb) * HH;  // within dir slice

  for (int s = 0; s < TT; ++s) {
    const int t_eff = d ? (TT - 1 - s) : s;

    HStage<32> st32; HStage<16> st16;
    const short* hsrc = (const short*)hbuf + ((size_t)(s & 1) * 2 + d) * (size_t)(BB * HH) + hrow0;
    if (NBT2) stage_issue<32>(st32, hsrc); else stage_issue<16>(st16, hsrc);

    // resolve per-half input sources (wave-uniform)
    const void* pl; size_t ol; int stl; int fl;
    const void* ph; size_t oh; int sth; int fh;
    if (d == 0) {
      pl = ysrc; ol = ((size_t)t_eff * BB + pass_off) * 1024; stl = 1024; fl = SRCF;
      if (USE_Y0 || s < 256) { ph = ysrc; oh = ol + HH; sth = 1024; fh = SRCF; }
      else { ph = stashB; oh = (size_t)(s - 256) * bcount * HH; sth = HH; fh = 1; }
    } else {
      ph = ysrc; oh = ((size_t)t_eff * BB + pass_off) * 1024 + HH; sth = 1024; fh = SRCF;
      if (USE_Y0 || s < 256) { pl = ysrc; ol = ((size_t)t_eff * BB + pass_off) * 1024; stl = 1024; fl = SRCF; }
      else { pl = stashF; ol = (size_t)t_eff * bcount * HH; stl = HH; fl = 1; }
    }

    f32x4 acc0 = {0.f, 0.f, 0.f, 0.f};
    f32x4 acc1 = {0.f, 0.f, 0.f, 0.f};
#pragma unroll
    for (int ks = 0; ks < 16; ++ks) {
      const size_t krel = (size_t)ks * 32 + kq;
      acc0 = mfma_a(wih[ks], ldab(pl, ol + (size_t)lb0 * stl + krel, fl), acc0);
      if (NBT2)
        acc1 = mfma_a(wih[ks], ldab(pl, ol + (size_t)(lb0 + 16) * stl + krel, fl), acc1);
    }
#pragma unroll
    for (int ks = 0; ks < 16; ++ks) {
      const size_t krel = (size_t)ks * 32 + kq;
      acc0 = mfma_a(wih[16 + ks], ldab(ph, oh + (size_t)lb0 * sth + krel, fh), acc0);
      if (NBT2)
        acc1 = mfma_a(wih[16 + ks], ldab(ph, oh + (size_t)(lb0 + 16) * sth + krel, fh), acc1);
    }
    if (NBT2) stage_commit<32>(st32, hs); else stage_commit<16>(st16, hs);
    __syncthreads();
#pragma unroll
    for (int ks = 0; ks < 16; ++ks) {
      const int kk = kq + ks * 32;
      acc0 = mfma_a(whh[ks], lds_frag(hs, nm, kk), acc0);
      if (NBT2) acc1 = mfma_a(whh[ks], lds_frag(hs, nm + 16, kk), acc1);
    }
    mfma_fence(acc0, acc1);
    {
      const int quad = lane >> 4;
#pragma unroll
      for (int r = 0; r < 4; ++r) {
        gx[g][quad * 4 + r][nm] = acc0[r];
        if (NBT2) gx[g][quad * 4 + r][16 + nm] = acc1[r];
      }
    }
    // In-place: all pristine out reads grid-wide before any out write.
    if (!USE_Y0) slotbar(slots, nblk, 2 * s + 1);
    else __syncthreads();

    {
      const float m = (t_eff < len) ? 1.0f : 0.0f;
      const int tn = d ? (t_eff - 1) : (t_eff + 1);
      const float mn = (tn >= 0 && tn < len) ? 1.0f : 0.0f;
      const size_t hoff = ((size_t)((s + 1) & 1) * 2 + d) * (size_t)(BB * HH) +
                          (size_t)b_g * HH + j_g;
      const size_t yb = ((size_t)t_eff * BB + b_g) * 1024 + (size_t)d * HH + j_g;
      if (NBT2) {
        float hva, hvb;
        LSTM_E(jq,     0, c0, hva);
        LSTM_E(jq + 1, 1, c1, hvb);
        unsigned int hp = (unsigned int)(unsigned short)f2bf(hva * mn) |
                          ((unsigned int)(unsigned short)f2bf(hvb * mn) << 16);
        __hip_atomic_store((unsigned int*)((short*)hbuf + hoff), hp,
                           __ATOMIC_RELAXED, __HIP_MEMORY_SCOPE_AGENT);
        if (ISBF) {
          unsigned int yp = (unsigned int)(unsigned short)f2bf(hva * m) |
                            ((unsigned int)(unsigned short)f2bf(hvb * m) << 16);
          *(unsigned int*)((short*)out + yb) = yp;
        } else {
          *(float2*)((float*)out + yb) = make_float2(hva * m, hvb * m);
        }
      } else {
        float hv;
        LSTM_E(jq, 0, c0, hv);
        unsigned short hu = (unsigned short)f2bf(hv * mn);
        int other = __shfl_xor((int)hu, 1);
        if ((tid & 1) == 0) {
          unsigned int hp = (unsigned int)hu | ((unsigned int)(unsigned short)other << 16);
          __hip_atomic_store((unsigned int*)((short*)hbuf + hoff), hp,
                             __ATOMIC_RELAXED, __HIP_MEMORY_SCOPE_AGENT);
        }
        if (ISBF) ((__hip_bfloat16*)out)[yb] = __float2bfloat16(hv * m);
        else      ((float*)out)[yb] = hv * m;
      }
    }
    if (s != TT - 1) slotbar(slots, nblk, USE_Y0 ? (s + 1) : (2 * s + 2));
  }
}

// ---------------------------------------------------------------------------
extern "C" void kernel_launch(void* const* d_in, const int* in_sizes, int n_in,
                              void* d_out, int out_size, void* d_ws, size_t ws_size,
                              hipStream_t stream) {
  (void)in_sizes; (void)n_in; (void)out_size;
  const void* x     = d_in[0];
  const int*  lens  = (const int*)d_in[1];
  const void* fWih0 = d_in[2];
  const void* fWhh0 = d_in[3];
  const void* fb0   = d_in[4];
  const void* bWih0 = d_in[5];
  const void* bWhh0 = d_in[6];
  const void* bb0   = d_in[7];
  const void* fWih1 = d_in[8];
  const void* fWhh1 = d_in[9];
  const void* fb1   = d_in[10];
  const void* bWih1 = d_in[11];
  const void* bWhh1 = d_in[12];
  const void* bb1   = d_in[13];
  void* out = d_out;

  // --- ws layout: [flag @0][slots 8KB @4096][rflag 8KB @12288][hb @32768][dyn] ---
  char* w = (char*)d_ws;
  int* flagp = (int*)w;
  int* slots = (int*)(w + 4096);
  __hip_bfloat16* hb = (__hip_bfloat16*)(w + 32768);
  const size_t HBYTES = (size_t)2 * 2 * BB * HH * sizeof(__hip_bfloat16); // 256 KiB
  char* dyn = w + 32768 + HBYTES;
  const size_t avail = (ws_size > 32768 + HBYTES) ? (ws_size - 32768 - HBYTES) : 0;

  const size_t XBF = (size_t)TT * BB * HH * 2;     // 32 MB bf16 x
  const size_t Y0B = (size_t)TT * BB * 1024 * 2;   // 64 MB bf16 y0

  sniff<<<1, 256, 0, stream>>>((const unsigned int*)x, flagp);

  if (avail >= XBF + Y0B) {
    // ---- Plan A: separate bf16 y0; out never read in l1 -> 1 barrier/step ----
    __hip_bfloat16* xbf = (__hip_bfloat16*)dyn;
    __hip_bfloat16* y0  = (__hip_bfloat16*)(dyn + XBF);
    conv_bf16<<<2048, 256, 0, stream>>>(x, xbf, flagp, (size_t)TT * BB * HH / 8);
    hipMemsetAsync(hb, 0, HBYTES, stream);
    hipMemsetAsync(w + 4096, 0, 16384, stream);
    l0_persist<0, 1><<<128, 256, 0, stream>>>(x, xbf, fWih0, fWhh0, fb0, bWih0, bWhh0, bb0,
                                              hb, lens, y0, flagp, slots);
    l0_persist<1, 1><<<128, 256, 0, stream>>>(x, xbf, fWih0, fWhh0, fb0, bWih0, bWhh0, bb0,
                                              hb, lens, y0, flagp, slots);
    hipMemsetAsync(hb, 0, HBYTES, stream);
    hipMemsetAsync(w + 4096, 0, 16384, stream);
    l1_persist<0, 1><<<128, 256, 0, stream>>>(fWih1, fWhh1, fb1, bWih1, bWhh1, bb1,
                                              y0, nullptr, nullptr, hb, lens, out,
                                              flagp, slots, 0, 32, 2, 64);
    l1_persist<1, 1><<<128, 256, 0, stream>>>(fWih1, fWhh1, fb1, bWih1, bWhh1, bb1,
                                              y0, nullptr, nullptr, hb, lens, out,
                                              flagp, slots, 0, 32, 2, 64);
  } else {
    // ---- Plans B/C/D: in-place out + bf16 stash of hazard halves ----
    const int bcount = (avail >= (size_t)64 * 524288) ? 64 :
                       (avail >= (size_t)32 * 524288) ? 32 : 16;
    const int nb  = (bcount == 64) ? 32 : 16;
    const int nbh = (bcount == 16) ? 1 : 2;
    __hip_bfloat16* stashF = (__hip_bfloat16*)dyn;
    __hip_bfloat16* stashB = stashF + (size_t)256 * bcount * HH;

    hipMemsetAsync(hb, 0, HBYTES, stream);
    hipMemsetAsync(w + 4096, 0, 16384, stream);
    l0_persist<0, 0><<<128, 256, 0, stream>>>(x, nullptr, fWih0, fWhh0, fb0, bWih0, bWhh0, bb0,
                                              hb, lens, out, flagp, slots);
    l0_persist<1, 0><<<128, 256, 0, stream>>>(x, nullptr, fWih0, fWhh0, fb0, bWih0, bWhh0, bb0,
                                              hb, lens, out, flagp, slots);
    const int P = 64 / bcount;
    for (int p = 0; p < P; ++p) {
      stash_fill<<<1024, 256, 0, stream>>>(out, stashF, stashB, flagp, bcount, p * bcount);
      hipMemsetAsync(hb, 0, HBYTES, stream);
      hipMemsetAsync(w + 4096, 0, 16384, stream);
      l1_persist<0, 0><<<64 * nbh, 256, 0, stream>>>(fWih1, fWhh1, fb1, bWih1, bWhh1, bb1,
                                                     out, stashF, stashB, hb, lens, out,
                                                     flagp, slots, p * bcount, nb, nbh, bcount);
      l1_persist<1, 0><<<64 * nbh, 256, 0, stream>>>(fWih1, fWhh1, fb1, bWih1, bWhh1, bb1,
                                                     out, stashF, stashB, hb, lens, out,
                                                     flagp, slots, p * bcount, nb, nbh, bcount);
    }
  }
}

// Round 4
// 11331.791 us; speedup vs baseline: 3.0713x; 1.0815x over previous
//
#include <hip/hip_runtime.h>
#include <hip/hip_bf16.h>
#include <cstddef>
#include <cstdint>

// Problem dims (fixed): T=512, B=64, D=H=512, gates = 4*H = 2048
#define TT 512
#define BB 64
#define HH 512

typedef __attribute__((ext_vector_type(8))) short bf16x8;   // 8 bf16 = 4 VGPRs
typedef __attribute__((ext_vector_type(4))) float f32x4;    // MFMA C/D
typedef __attribute__((ext_vector_type(4))) int   i32x4;    // 16B staging reg

__device__ __forceinline__ float sigf(float x) { return 1.0f / (1.0f + __expf(-x)); }
__device__ __forceinline__ float tanhfast(float x) { return 2.0f / (1.0f + __expf(-2.0f * x)) - 1.0f; }

// fp32 -> bf16 (round-nearest-even), as raw short
__device__ __forceinline__ short f2bf(float x) {
  uint32_t u = __float_as_uint(x);
  u += 0x7FFFu + ((u >> 16) & 1u);
  return (short)(u >> 16);
}

// MFMA with weight operand PINNED to AGPRs ("a" constraint). s_nop 1 covers
// the VALU-write -> MFMA-srcB hazard (fp32->bf16 convert feeding B).
__device__ __forceinline__ f32x4 mfma_a(bf16x8 w, bf16x8 b, f32x4 acc) {
  asm("s_nop 1\n\tv_mfma_f32_16x16x32_bf16 %0, %1, %2, %0"
      : "+v"(acc) : "a"(w), "v"(b));
  return acc;
}
// Data-dependent hazard fence before VALU reads of the accumulators.
__device__ __forceinline__ void mfma_fence(f32x4& a0, f32x4& a1) {
  asm volatile("s_nop 7\n\ts_nop 7\n\ts_nop 7" : "+v"(a0), "+v"(a1));
}

// Adaptive 8-element fragment load (element-indexed). isbf: 1 = bf16, 0 = fp32.
__device__ __forceinline__ bf16x8 ldab(const void* base, size_t e, int isbf) {
  if (isbf) return *(const bf16x8*)((const short*)base + e);
  const float* f = (const float*)base + e;
  float4 a = *(const float4*)f;
  float4 b = *(const float4*)(f + 4);
  bf16x8 r;
  r[0] = f2bf(a.x); r[1] = f2bf(a.y); r[2] = f2bf(a.z); r[3] = f2bf(a.w);
  r[4] = f2bf(b.x); r[5] = f2bf(b.y); r[6] = f2bf(b.z); r[7] = f2bf(b.w);
  return r;
}

__device__ __forceinline__ float ldsc(const void* base, size_t e, int isbf) {
  if (isbf) return (float)((const __hip_bfloat16*)base)[e];
  return ((const float*)base)[e];
}

// ---------------------------------------------------------------------------
// Dtype sniffer (proven): majority-vote on bf16-pair exponent bits.
// ---------------------------------------------------------------------------
__global__ __launch_bounds__(256) void sniff(const unsigned int* __restrict__ x,
                                             int* __restrict__ flag) {
  __shared__ int cnt[256];
  int c = 0;
#pragma unroll
  for (int i = 0; i < 16; ++i) {
    unsigned w = x[threadIdx.x * 16 + i];
    unsigned e = (w >> 7) & 0xFFu;
    c += (e >= 110u && e <= 140u) ? 1 : 0;
  }
  cnt[threadIdx.x] = c;
  __syncthreads();
  for (int s = 128; s > 0; s >>= 1) {
    if ((int)threadIdx.x < s) cnt[threadIdx.x] += cnt[threadIdx.x + s];
    __syncthreads();
  }
  if (threadIdx.x == 0) flag[0] = (cnt[0] > 2048) ? 1 : 0;
}

// ---------------------------------------------------------------------------
// Split group barrier (per dependency group, 32 or 64 blocks), one-phase
// all-to-all: arrival = own-slot store (64B-spread, no line contention);
// wait = wave-0 lanes poll all group slots in parallel (1 vector load/iter,
// no release fan-out round-trip). bar_arrive's __syncthreads drains each
// wave's vmcnt (compiler emits s_waitcnt vmcnt(0) before s_barrier), so the
// agent-scope h stores are at the coherent point before the slot store.
// Between arrive and wait, barrier-independent work (Wih MFMAs over
// read-only/pristine inputs) hides the MALL propagation latency.
// ---------------------------------------------------------------------------
__device__ __forceinline__ void bar_arrive(int* __restrict__ gslots, int lidx, int gen) {
  __syncthreads();
  if (threadIdx.x == 0)
    __hip_atomic_store(&gslots[lidx * 16], gen, __ATOMIC_RELAXED, __HIP_MEMORY_SCOPE_AGENT);
}

__device__ __forceinline__ void bar_wait(int* __restrict__ gslots, int gsize, int gen) {
  if ((int)threadIdx.x < gsize) {
    while (__hip_atomic_load(&gslots[threadIdx.x * 16], __ATOMIC_RELAXED, __HIP_MEMORY_SCOPE_AGENT) < gen)
      __builtin_amdgcn_s_sleep(1);
  }
  __syncthreads();
}

// ---------------------------------------------------------------------------
// Split coherent h-slice staging: issue (L1/L2-bypass loads into regs) early,
// commit (waitcnt + swizzled LDS write) later. LDS XOR-swizzled
// (byte ^= (row&7)<<4) so MFMA fragment reads don't bank-conflict.
// ---------------------------------------------------------------------------
template<int NR>
struct HStage { i32x4 tmp[NR * 64 / 256]; };

template<int NR>
__device__ __forceinline__ void stage_issue(HStage<NR>& st, const short* __restrict__ hsrc) {
  const int tid = threadIdx.x;
#pragma unroll
  for (int i = 0; i < NR * 64 / 256; ++i) {
    const short* p = hsrc + (size_t)(tid + i * 256) * 8;
    asm volatile("global_load_dwordx4 %0, %1, off sc0 sc1" : "=v"(st.tmp[i]) : "v"(p));
  }
}

template<int NR>
__device__ __forceinline__ void stage_commit(HStage<NR>& st, short* __restrict__ hs) {
  const int tid = threadIdx.x;
  asm volatile("s_waitcnt vmcnt(0)" ::: "memory");
  __builtin_amdgcn_sched_barrier(0);
#pragma unroll
  for (int i = 0; i < NR * 64 / 256; ++i) {
    const int c = tid + i * 256;
    const int row = c >> 6;              // 64 chunks per row
    const int wb  = (c & 63) << 4;       // byte within row
    *(i32x4*)((char*)hs + (size_t)row * 1024 + (size_t)(wb ^ ((row & 7) << 4))) = st.tmp[i];
  }
}

// Swizzled LDS fragment read: row r, element offset kk (multiple of 8).
__device__ __forceinline__ bf16x8 lds_frag(const short* __restrict__ hs, int r, int kk) {
  return *(const bf16x8*)(hs + r * HH + (kk ^ ((r & 7) << 3)));
}

// ---------------------------------------------------------------------------
// Elementwise convert-to-bf16 (Plan A: x -> x_bf). Copies if already bf16.
// ---------------------------------------------------------------------------
__global__ __launch_bounds__(256) void conv_bf16(const void* __restrict__ src,
                                                 __hip_bfloat16* __restrict__ dst,
                                                 const int* __restrict__ flagp,
                                                 size_t n8) {
  const int isbf = flagp[0];
  for (size_t i = (size_t)blockIdx.x * 256 + threadIdx.x; i < n8;
       i += (size_t)gridDim.x * 256) {
    bf16x8 v = ldab(src, i * 8, isbf);
    *(bf16x8*)((short*)dst + i * 8) = v;
  }
}

// ---------------------------------------------------------------------------
// Stash fill (Plans B/C/D): snapshot hazard halves of this pass's b-columns
// from pristine y0 (in out) into bf16 stash.
// ---------------------------------------------------------------------------
__global__ __launch_bounds__(256) void stash_fill(
    const void* __restrict__ out,
    __hip_bfloat16* __restrict__ stashF,
    __hip_bfloat16* __restrict__ stashB,
    const int* __restrict__ flagp,
    int bcount, int pass_off)
{
  const int isbf = flagp[0];
  const size_t total8 = (size_t)2 * 256 * bcount * HH / 8;
  for (size_t i = (size_t)blockIdx.x * 256 + threadIdx.x; i < total8;
       i += (size_t)gridDim.x * 256) {
    const size_t idx = i * 8;
    const int k = (int)(idx & 511);
    const size_t r = idx >> 9;
    const int lb = (int)(r % bcount);
    const size_t rr = r / bcount;
    const int row = (int)(rr & 255);
    const bool isB = rr >= 256;
    const size_t src = ((size_t)(isB ? (256 + row) : row) * BB + pass_off + lb) * 1024 +
                       (isB ? HH : 0) + k;
    bf16x8 v = ldab(out, src, isbf);
    __hip_bfloat16* dst = (isB ? stashB : stashF) + ((size_t)row * bcount + lb) * HH + k;
    *(bf16x8*)(void*)dst = v;
  }
}

// LSTM cell element update (shared by both layers).
#define LSTM_E(JL, BR, CREF, H2) do { \
    float vi = gx[0][JL][ub] + bias_r[0][BR]; \
    float vf = gx[1][JL][ub] + bias_r[1][BR]; \
    float vg = gx[2][JL][ub] + bias_r[2][BR]; \
    float vo = gx[3][JL][ub] + bias_r[3][BR]; \
    const float cold = (CREF) * m; \
    const float c2 = sigf(vf) * cold + sigf(vi) * tanhfast(vg); \
    (H2) = sigf(vo) * tanhfast(c2); \
    (CREF) = c2; \
  } while (0)

// ---------------------------------------------------------------------------
// PERSISTENT LAYER 0. Grid 128 = dir(2) x jtile(32) x bhalf(2), 256 thr.
// Weights in AGPRs; c-state in regs. h-coupling is closed within the
// (dir, bhalf) group of 32 blocks -> per-group barrier. One arrive/wait pair
// per step, with the Wih section (x is read-only) between them.
// ---------------------------------------------------------------------------
template<int ISBF, int USE_XBF>
__global__ __launch_bounds__(256, 1) void l0_persist(
    const void* __restrict__ x,
    const __hip_bfloat16* __restrict__ xbf,
    const void* __restrict__ Wih_f, const void* __restrict__ Whh_f, const void* __restrict__ bias_f,
    const void* __restrict__ Wih_b, const void* __restrict__ Whh_b, const void* __restrict__ bias_b,
    __hip_bfloat16* __restrict__ hbuf,   // [2 par][2 dir][64][512] bf16
    const int* __restrict__ lens,
    void* __restrict__ ydst,             // Plan A: y0_bf (bf16); else out (dtype)
    const int* __restrict__ flagp,
    int* __restrict__ slots)
{
  if (flagp[0] != ISBF) return;

  const int bx = blockIdx.x;
  const int d  = bx >> 6;
  const int jt = (bx >> 1) & 31;
  const int bh = bx & 1;
  int* gslots = slots + (d * 2 + bh) * 1024;   // 4 groups of 32
  const int lidx = jt;

  const void* Wih  = d ? Wih_b  : Wih_f;
  const void* Whh  = d ? Whh_b  : Whh_f;
  const void* bias = d ? bias_b : bias_f;

  const int tid  = threadIdx.x;
  const int lane = tid & 63;
  const int g    = tid >> 6;          // wave = gate (i,f,g,o)
  const int nm   = lane & 15;
  const int kq   = (lane >> 4) * 8;

  // ---- one-time: weights -> AGPRs ----
  bf16x8 wih[16], whh[16];
  {
    const size_t arow = (size_t)(g * HH + jt * 16 + nm) * HH + kq;
#pragma unroll
    for (int ks = 0; ks < 16; ++ks) {
      wih[ks] = ldab(Wih, arow + ks * 32, ISBF);
      whh[ks] = ldab(Whh, arow + ks * 32, ISBF);
    }
  }

  const void* xs = USE_XBF ? (const void*)xbf : x;
  const int   XF = USE_XBF ? 1 : ISBF;
  const int  YBF = USE_XBF ? 1 : ISBF;

  // update-phase statics
  const int ub  = tid >> 3;              // local batch 0..31
  const int jq  = (tid & 7) * 2;         // j pair base
  const int b_g = bh * 32 + ub;
  const int j_g = jt * 16 + jq;
  const int len = lens[b_g];
  float bias_r[4][2];
#pragma unroll
  for (int q = 0; q < 4; ++q) {
    bias_r[q][0] = ldsc(bias, q * HH + j_g, ISBF);
    bias_r[q][1] = ldsc(bias, q * HH + j_g + 1, ISBF);
  }
  float c0 = 0.f, c1 = 0.f;

  __shared__ float gx[4][16][33];
  __shared__ __align__(16) short hs[32 * HH];

  const size_t hrow0 = (size_t)(bh * 32) * HH;   // within dir slice

  for (int s = 0; s < TT; ++s) {
    const int t_eff = d ? (TT - 1 - s) : s;

    // ---- Wih section (barrier-independent): overlaps barrier propagation ----
    f32x4 acc0 = {0.f, 0.f, 0.f, 0.f};
    f32x4 acc1 = {0.f, 0.f, 0.f, 0.f};
    const size_t xo0 = ((size_t)t_eff * BB + bh * 32 + nm) * HH + kq;
    const size_t xo1 = xo0 + (size_t)16 * HH;
#pragma unroll
    for (int ks = 0; ks < 12; ++ks) {
      acc0 = mfma_a(wih[ks], ldab(xs, xo0 + ks * 32, XF), acc0);
      acc1 = mfma_a(wih[ks], ldab(xs, xo1 + ks * 32, XF), acc1);
    }
    bar_wait(gslots, 32, s);                 // h(s) now group-visible
    HStage<32> st;
    const short* hsrc = (const short*)hbuf + ((size_t)(s & 1) * 2 + d) * (size_t)(BB * HH) + hrow0;
    stage_issue<32>(st, hsrc);
#pragma unroll
    for (int ks = 12; ks < 16; ++ks) {
      acc0 = mfma_a(wih[ks], ldab(xs, xo0 + ks * 32, XF), acc0);
      acc1 = mfma_a(wih[ks], ldab(xs, xo1 + ks * 32, XF), acc1);
    }
    stage_commit<32>(st, hs);
    __syncthreads();
#pragma unroll
    for (int ks = 0; ks < 16; ++ks) {
      const int kk = kq + ks * 32;
      acc0 = mfma_a(whh[ks], lds_frag(hs, nm, kk), acc0);
      acc1 = mfma_a(whh[ks], lds_frag(hs, nm + 16, kk), acc1);
    }
    mfma_fence(acc0, acc1);
    {
      const int quad = lane >> 4;
#pragma unroll
      for (int r = 0; r < 4; ++r) {
        gx[g][quad * 4 + r][nm]      = acc0[r];
        gx[g][quad * 4 + r][16 + nm] = acc1[r];
      }
    }
    __syncthreads();

    // ---- fused update ----
    {
      const float m = (t_eff < len) ? 1.0f : 0.0f;
      const int tn = d ? (t_eff - 1) : (t_eff + 1);
      const float mn = (tn >= 0 && tn < len) ? 1.0f : 0.0f;
      float hva, hvb;
      LSTM_E(jq,     0, c0, hva);
      LSTM_E(jq + 1, 1, c1, hvb);
      unsigned int hp = (unsigned int)(unsigned short)f2bf(hva * mn) |
                        ((unsigned int)(unsigned short)f2bf(hvb * mn) << 16);
      unsigned int* hnxt = (unsigned int*)((short*)hbuf +
          ((size_t)((s + 1) & 1) * 2 + d) * (size_t)(BB * HH) + (size_t)b_g * HH + j_g);
      __hip_atomic_store(hnxt, hp, __ATOMIC_RELAXED, __HIP_MEMORY_SCOPE_AGENT);
      const size_t yb = ((size_t)t_eff * BB + b_g) * 1024 + (size_t)d * HH + j_g;
      if (YBF) {
        unsigned int yp = (unsigned int)(unsigned short)f2bf(hva * m) |
                          ((unsigned int)(unsigned short)f2bf(hvb * m) << 16);
        *(unsigned int*)((short*)ydst + yb) = yp;
      } else {
        *(float2*)((float*)ydst + yb) = make_float2(hva * m, hvb * m);
      }
    }
    if (s != TT - 1) bar_arrive(gslots, lidx, s + 1);
  }
}

// ---------------------------------------------------------------------------
// PERSISTENT LAYER 1. Grid 64*nbh. Weights in AGPRs (192 frags).
// USE_Y0 (Plan A): y0 read-only, out never read -> (dir,bh) groups of 32.
// In-place: fwd-writes couple with bwd-pristine-reads -> bh groups of 64;
// out-row writes DEFERRED one step (flush after next bar_wait), so all
// grid reads of a row complete (arrivals) before its write -> single
// barrier per step. Pristine/stash reads are safe before bar_wait.
// ---------------------------------------------------------------------------
template<int ISBF, int USE_Y0>
__global__ __launch_bounds__(256, 1) void l1_persist(
    const void* __restrict__ Wih_f, const void* __restrict__ Whh_f, const void* __restrict__ bias_f,
    const void* __restrict__ Wih_b, const void* __restrict__ Whh_b, const void* __restrict__ bias_b,
    const void* __restrict__ ysrc,   // out (in-place) or y0_bf (Plan A)
    const __hip_bfloat16* __restrict__ stashF,
    const __hip_bfloat16* __restrict__ stashB,
    __hip_bfloat16* __restrict__ hbuf,
    const int* __restrict__ lens,
    void* __restrict__ out,
    const int* __restrict__ flagp,
    int* __restrict__ slots,
    int pass_off, int nb, int nbh, int bcount)
{
  if (flagp[0] != ISBF) return;

  const int bx = blockIdx.x;
  const int d   = bx / (32 * nbh);
  const int rem = bx % (32 * nbh);
  const int jt  = rem / nbh;
  const int bh  = rem % nbh;

  // groups: Plan A -> (d,bh) 32-block groups; in-place -> bh 64-block groups
  int* gslots;
  int lidx, gsize;
  if (USE_Y0) { gslots = slots + (d * 2 + bh) * 1024; lidx = jt;          gsize = 32; }
  else        { gslots = slots + bh * 1024;           lidx = d * 32 + jt; gsize = 64; }

  const void* Wih  = d ? Wih_b  : Wih_f;
  const void* Whh  = d ? Whh_b  : Whh_f;
  const void* bias = d ? bias_b : bias_f;

  const int tid  = threadIdx.x;
  const int lane = tid & 63;
  const int g    = tid >> 6;
  const int nm   = lane & 15;
  const int kq   = (lane >> 4) * 8;

  // ---- one-time: weights -> AGPRs ----
  bf16x8 wih[32], whh[16];
  {
    const size_t arow_ih = (size_t)(g * HH + jt * 16 + nm) * 1024 + kq;
    const size_t arow_hh = (size_t)(g * HH + jt * 16 + nm) * HH + kq;
#pragma unroll
    for (int ks = 0; ks < 32; ++ks) wih[ks] = ldab(Wih, arow_ih + ks * 32, ISBF);
#pragma unroll
    for (int ks = 0; ks < 16; ++ks) whh[ks] = ldab(Whh, arow_hh + ks * 32, ISBF);
  }

  const bool NBT2 = (nb == 32);
  const int lb0 = bh * nb + nm;          // local batch row
  const int SRCF = USE_Y0 ? 1 : ISBF;

  const int ub  = NBT2 ? (tid >> 3) : (tid >> 4);
  const int jq  = NBT2 ? ((tid & 7) * 2) : (tid & 15);
  const int b_g = pass_off + bh * nb + ub;
  const int j_g = jt * 16 + jq;
  const int len = lens[b_g];
  float bias_r[4][2];
#pragma unroll
  for (int q = 0; q < 4; ++q) {
    bias_r[q][0] = ldsc(bias, q * HH + j_g, ISBF);
    bias_r[q][1] = NBT2 ? ldsc(bias, q * HH + j_g + 1, ISBF) : 0.f;
  }
  float c0 = 0.f, c1 = 0.f;

  // deferred out-write state (in-place only)
  int   pend_t = -1;
  float pend0 = 0.f, pend1 = 0.f;

  __shared__ float gx[4][16][33];
  __shared__ __align__(16) short hs[32 * HH];

  const size_t hrow0 = (size_t)(pass_off + bh * nb) * HH;  // within dir slice

  for (int s = 0; s < TT; ++s) {
    const int t_eff = d ? (TT - 1 - s) : s;

    // resolve per-half input sources (wave-uniform)
    const void* pl; size_t ol; int stl; int fl;
    const void* ph; size_t oh; int sth; int fh;
    if (d == 0) {
      pl = ysrc; ol = ((size_t)t_eff * BB + pass_off) * 1024; stl = 1024; fl = SRCF;
      if (USE_Y0 || s < 256) { ph = ysrc; oh = ol + HH; sth = 1024; fh = SRCF; }
      else { ph = stashB; oh = (size_t)(s - 256) * bcount * HH; sth = HH; fh = 1; }
    } else {
      ph = ysrc; oh = ((size_t)t_eff * BB + pass_off) * 1024 + HH; sth = 1024; fh = SRCF;
      if (USE_Y0 || s < 256) { pl = ysrc; ol = ((size_t)t_eff * BB + pass_off) * 1024; stl = 1024; fl = SRCF; }
      else { pl = stashF; ol = (size_t)t_eff * bcount * HH; stl = HH; fl = 1; }
    }

    // ---- Wih sections (pristine/stash reads: safe before bar_wait) ----
    f32x4 acc0 = {0.f, 0.f, 0.f, 0.f};
    f32x4 acc1 = {0.f, 0.f, 0.f, 0.f};
#pragma unroll
    for (int ks = 0; ks < 16; ++ks) {
      const size_t krel = (size_t)ks * 32 + kq;
      acc0 = mfma_a(wih[ks], ldab(pl, ol + (size_t)lb0 * stl + krel, fl), acc0);
      if (NBT2)
        acc1 = mfma_a(wih[ks], ldab(pl, ol + (size_t)(lb0 + 16) * stl + krel, fl), acc1);
    }
#pragma unroll
    for (int ks = 0; ks < 12; ++ks) {
      const size_t krel = (size_t)ks * 32 + kq;
      acc0 = mfma_a(wih[16 + ks], ldab(ph, oh + (size_t)lb0 * sth + krel, fh), acc0);
      if (NBT2)
        acc1 = mfma_a(wih[16 + ks], ldab(ph, oh + (size_t)(lb0 + 16) * sth + krel, fh), acc1);
    }
    bar_wait(gslots, gsize, s);              // h(s) visible; row reads of s-1 done
    HStage<32> st32; HStage<16> st16;
    const short* hsrc = (const short*)hbuf + ((size_t)(s & 1) * 2 + d) * (size_t)(BB * HH) + hrow0;
    if (NBT2) stage_issue<32>(st32, hsrc); else stage_issue<16>(st16, hsrc);
    // flush deferred out-row (in-place): all group reads of it completed
    if (!USE_Y0 && pend_t >= 0) {
      const size_t yb = ((size_t)pend_t * BB + b_g) * 1024 + (size_t)d * HH + j_g;
      if (ISBF) {
        if (NBT2) {
          unsigned int yp = (unsigned int)(unsigned short)f2bf(pend0) |
                            ((unsigned int)(unsigned short)f2bf(pend1) << 16);
          *(unsigned int*)((short*)out + yb) = yp;
        } else ((__hip_bfloat16*)out)[yb] = __float2bfloat16(pend0);
      } else {
        if (NBT2) *(float2*)((float*)out + yb) = make_float2(pend0, pend1);
        else      ((float*)out)[yb] = pend0;
      }
    }
#pragma unroll
    for (int ks = 12; ks < 16; ++ks) {
      const size_t krel = (size_t)ks * 32 + kq;
      acc0 = mfma_a(wih[16 + ks], ldab(ph, oh + (size_t)lb0 * sth + krel, fh), acc0);
      if (NBT2)
        acc1 = mfma_a(wih[16 + ks], ldab(ph, oh + (size_t)(lb0 + 16) * sth + krel, fh), acc1);
    }
    if (NBT2) stage_commit<32>(st32, hs); else stage_commit<16>(st16, hs);
    __syncthreads();
#pragma unroll
    for (int ks = 0; ks < 16; ++ks) {
      const int kk = kq + ks * 32;
      acc0 = mfma_a(whh[ks], lds_frag(hs, nm, kk), acc0);
      if (NBT2) acc1 = mfma_a(whh[ks], lds_frag(hs, nm + 16, kk), acc1);
    }
    mfma_fence(acc0, acc1);
    {
      const int quad = lane >> 4;
#pragma unroll
      for (int r = 0; r < 4; ++r) {
        gx[g][quad * 4 + r][nm] = acc0[r];
        if (NBT2) gx[g][quad * 4 + r][16 + nm] = acc1[r];
      }
    }
    __syncthreads();

    // ---- fused update: h store now, out write deferred (in-place) ----
    {
      const float m = (t_eff < len) ? 1.0f : 0.0f;
      const int tn = d ? (t_eff - 1) : (t_eff + 1);
      const float mn = (tn >= 0 && tn < len) ? 1.0f : 0.0f;
      const size_t hoff = ((size_t)((s + 1) & 1) * 2 + d) * (size_t)(BB * HH) +
                          (size_t)b_g * HH + j_g;
      if (NBT2) {
        float hva, hvb;
        LSTM_E(jq,     0, c0, hva);
        LSTM_E(jq + 1, 1, c1, hvb);
        unsigned int hp = (unsigned int)(unsigned short)f2bf(hva * mn) |
                          ((unsigned int)(unsigned short)f2bf(hvb * mn) << 16);
        __hip_atomic_store((unsigned int*)((short*)hbuf + hoff), hp,
                           __ATOMIC_RELAXED, __HIP_MEMORY_SCOPE_AGENT);
        if (USE_Y0) {
          const size_t yb = ((size_t)t_eff * BB + b_g) * 1024 + (size_t)d * HH + j_g;
          if (ISBF) {
            unsigned int yp = (unsigned int)(unsigned short)f2bf(hva * m) |
                              ((unsigned int)(unsigned short)f2bf(hvb * m) << 16);
            *(unsigned int*)((short*)out + yb) = yp;
          } else {
            *(float2*)((float*)out + yb) = make_float2(hva * m, hvb * m);
          }
        } else {
          pend0 = hva * m; pend1 = hvb * m; pend_t = t_eff;
        }
      } else {
        float hv;
        LSTM_E(jq, 0, c0, hv);
        unsigned short hu = (unsigned short)f2bf(hv * mn);
        int other = __shfl_xor((int)hu, 1);
        if ((tid & 1) == 0) {
          unsigned int hp = (unsigned int)hu | ((unsigned int)(unsigned short)other << 16);
          __hip_atomic_store((unsigned int*)((short*)hbuf + hoff), hp,
                             __ATOMIC_RELAXED, __HIP_MEMORY_SCOPE_AGENT);
        }
        if (USE_Y0) {
          const size_t yb = ((size_t)t_eff * BB + b_g) * 1024 + (size_t)d * HH + j_g;
          if (ISBF) ((__hip_bfloat16*)out)[yb] = __float2bfloat16(hv * m);
          else      ((float*)out)[yb] = hv * m;
        } else {
          pend0 = hv * m; pend_t = t_eff;
        }
      }
    }
    if (s != TT - 1) bar_arrive(gslots, lidx, s + 1);
  }

  // final deferred flush (in-place)
  if (!USE_Y0 && pend_t >= 0) {
    const size_t yb = ((size_t)pend_t * BB + b_g) * 1024 + (size_t)d * HH + j_g;
    if (ISBF) {
      if (NBT2) {
        unsigned int yp = (unsigned int)(unsigned short)f2bf(pend0) |
                          ((unsigned int)(unsigned short)f2bf(pend1) << 16);
        *(unsigned int*)((short*)out + yb) = yp;
      } else ((__hip_bfloat16*)out)[yb] = __float2bfloat16(pend0);
    } else {
      if (NBT2) *(float2*)((float*)out + yb) = make_float2(pend0, pend1);
      else      ((float*)out)[yb] = pend0;
    }
  }
}

// ---------------------------------------------------------------------------
extern "C" void kernel_launch(void* const* d_in, const int* in_sizes, int n_in,
                              void* d_out, int out_size, void* d_ws, size_t ws_size,
                              hipStream_t stream) {
  (void)in_sizes; (void)n_in; (void)out_size;
  const void* x     = d_in[0];
  const int*  lens  = (const int*)d_in[1];
  const void* fWih0 = d_in[2];
  const void* fWhh0 = d_in[3];
  const void* fb0   = d_in[4];
  const void* bWih0 = d_in[5];
  const void* bWhh0 = d_in[6];
  const void* bb0   = d_in[7];
  const void* fWih1 = d_in[8];
  const void* fWhh1 = d_in[9];
  const void* fb1   = d_in[10];
  const void* bWih1 = d_in[11];
  const void* bWhh1 = d_in[12];
  const void* bb1   = d_in[13];
  void* out = d_out;

  // --- ws layout: [flag @0][slots 16KB @4096][hb @32768][dyn] ---
  char* w = (char*)d_ws;
  int* flagp = (int*)w;
  int* slots = (int*)(w + 4096);
  __hip_bfloat16* hb = (__hip_bfloat16*)(w + 32768);
  const size_t HBYTES = (size_t)2 * 2 * BB * HH * sizeof(__hip_bfloat16); // 256 KiB
  char* dyn = w + 32768 + HBYTES;
  const size_t avail = (ws_size > 32768 + HBYTES) ? (ws_size - 32768 - HBYTES) : 0;

  const size_t XBF = (size_t)TT * BB * HH * 2;     // 32 MB bf16 x
  const size_t Y0B = (size_t)TT * BB * 1024 * 2;   // 64 MB bf16 y0

  sniff<<<1, 256, 0, stream>>>((const unsigned int*)x, flagp);

  if (avail >= XBF + Y0B) {
    // ---- Plan A: separate bf16 y0; out never read in l1 ----
    __hip_bfloat16* xbf = (__hip_bfloat16*)dyn;
    __hip_bfloat16* y0  = (__hip_bfloat16*)(dyn + XBF);
    conv_bf16<<<2048, 256, 0, stream>>>(x, xbf, flagp, (size_t)TT * BB * HH / 8);
    hipMemsetAsync(hb, 0, HBYTES, stream);
    hipMemsetAsync(w + 4096, 0, 16384, stream);
    l0_persist<0, 1><<<128, 256, 0, stream>>>(x, xbf, fWih0, fWhh0, fb0, bWih0, bWhh0, bb0,
                                              hb, lens, y0, flagp, slots);
    l0_persist<1, 1><<<128, 256, 0, stream>>>(x, xbf, fWih0, fWhh0, fb0, bWih0, bWhh0, bb0,
                                              hb, lens, y0, flagp, slots);
    hipMemsetAsync(hb, 0, HBYTES, stream);
    hipMemsetAsync(w + 4096, 0, 16384, stream);
    l1_persist<0, 1><<<128, 256, 0, stream>>>(fWih1, fWhh1, fb1, bWih1, bWhh1, bb1,
                                              y0, nullptr, nullptr, hb, lens, out,
                                              flagp, slots, 0, 32, 2, 64);
    l1_persist<1, 1><<<128, 256, 0, stream>>>(fWih1, fWhh1, fb1, bWih1, bWhh1, bb1,
                                              y0, nullptr, nullptr, hb, lens, out,
                                              flagp, slots, 0, 32, 2, 64);
  } else {
    // ---- Plans B/C/D: in-place out + bf16 stash of hazard halves ----
    const int bcount = (avail >= (size_t)64 * 524288) ? 64 :
                       (avail >= (size_t)32 * 524288) ? 32 : 16;
    const int nb  = (bcount == 64) ? 32 : 16;
    const int nbh = (bcount == 16) ? 1 : 2;
    __hip_bfloat16* stashF = (__hip_bfloat16*)dyn;
    __hip_bfloat16* stashB = stashF + (size_t)256 * bcount * HH;

    hipMemsetAsync(hb, 0, HBYTES, stream);
    hipMemsetAsync(w + 4096, 0, 16384, stream);
    l0_persist<0, 0><<<128, 256, 0, stream>>>(x, nullptr, fWih0, fWhh0, fb0, bWih0, bWhh0, bb0,
                                              hb, lens, out, flagp, slots);
    l0_persist<1, 0><<<128, 256, 0, stream>>>(x, nullptr, fWih0, fWhh0, fb0, bWih0, bWhh0, bb0,
                                              hb, lens, out, flagp, slots);
    const int P = 64 / bcount;
    for (int p = 0; p < P; ++p) {
      stash_fill<<<1024, 256, 0, stream>>>(out, stashF, stashB, flagp, bcount, p * bcount);
      hipMemsetAsync(hb, 0, HBYTES, stream);
      hipMemsetAsync(w + 4096, 0, 16384, stream);
      l1_persist<0, 0><<<64 * nbh, 256, 0, stream>>>(fWih1, fWhh1, fb1, bWih1, bWhh1, bb1,
                                                     out, stashF, stashB, hb, lens, out,
                                                     flagp, slots, p * bcount, nb, nbh, bcount);
      l1_persist<1, 0><<<64 * nbh, 256, 0, stream>>>(fWih1, fWhh1, fb1, bWih1, bWhh1, bb1,
                                                     out, stashF, stashB, hb, lens, out,
                                                     flagp, slots, p * bcount, nb, nbh, bcount);
    }
  }
}

// Round 5
// 3536.634 us; speedup vs baseline: 9.8409x; 3.2041x over previous
//
#include <hip/hip_runtime.h>
#include <hip/hip_bf16.h>
#include <cstddef>
#include <cstdint>

// Problem dims (fixed): T=512, B=64, D=H=512, gates = 4*H = 2048
#define TT 512
#define BB 64
#define HH 512

typedef __attribute__((ext_vector_type(8))) short bf16x8;   // 8 bf16 = 4 VGPRs
typedef __attribute__((ext_vector_type(4))) float f32x4;    // MFMA C/D
typedef __attribute__((ext_vector_type(4))) int   i32x4;    // 16B staging reg

__device__ __forceinline__ float sigf(float x) { return 1.0f / (1.0f + __expf(-x)); }
__device__ __forceinline__ float tanhfast(float x) { return 2.0f / (1.0f + __expf(-2.0f * x)) - 1.0f; }

// fp32 -> bf16 (round-nearest-even), as raw short
__device__ __forceinline__ short f2bf(float x) {
  uint32_t u = __float_as_uint(x);
  u += 0x7FFFu + ((u >> 16) & 1u);
  return (short)(u >> 16);
}

// MFMA with weight operand PINNED to AGPRs ("a" constraint). s_nop 1 covers
// any VALU-write -> MFMA-src hazard the compiler can't see inside asm.
__device__ __forceinline__ f32x4 mfma_a(bf16x8 w, bf16x8 b, f32x4 acc) {
  asm("s_nop 1\n\tv_mfma_f32_16x16x32_bf16 %0, %1, %2, %0"
      : "+v"(acc) : "a"(w), "v"(b));
  return acc;
}
// Data-dependent hazard fence before VALU reads of the accumulators.
__device__ __forceinline__ void mfma_fence(f32x4& a0, f32x4& a1) {
  asm volatile("s_nop 7\n\ts_nop 7\n\ts_nop 7" : "+v"(a0), "+v"(a1));
}

// Adaptive 8-element fragment load (element-indexed). isbf: 1 = bf16, 0 = fp32.
__device__ __forceinline__ bf16x8 ldab(const void* base, size_t e, int isbf) {
  if (isbf) return *(const bf16x8*)((const short*)base + e);
  const float* f = (const float*)base + e;
  float4 a = *(const float4*)f;
  float4 b = *(const float4*)(f + 4);
  bf16x8 r;
  r[0] = f2bf(a.x); r[1] = f2bf(a.y); r[2] = f2bf(a.z); r[3] = f2bf(a.w);
  r[4] = f2bf(b.x); r[5] = f2bf(b.y); r[6] = f2bf(b.z); r[7] = f2bf(b.w);
  return r;
}

__device__ __forceinline__ float ldsc(const void* base, size_t e, int isbf) {
  if (isbf) return (float)((const __hip_bfloat16*)base)[e];
  return ((const float*)base)[e];
}

// ---------------------------------------------------------------------------
// Dtype sniffer (proven): majority-vote on bf16-pair exponent bits.
// ---------------------------------------------------------------------------
__global__ __launch_bounds__(256) void sniff(const unsigned int* __restrict__ x,
                                             int* __restrict__ flag) {
  __shared__ int cnt[256];
  int c = 0;
#pragma unroll
  for (int i = 0; i < 16; ++i) {
    unsigned w = x[threadIdx.x * 16 + i];
    unsigned e = (w >> 7) & 0xFFu;
    c += (e >= 110u && e <= 140u) ? 1 : 0;
  }
  cnt[threadIdx.x] = c;
  __syncthreads();
  for (int s = 128; s > 0; s >>= 1) {
    if ((int)threadIdx.x < s) cnt[threadIdx.x] += cnt[threadIdx.x + s];
    __syncthreads();
  }
  if (threadIdx.x == 0) flag[0] = (cnt[0] > 2048) ? 1 : 0;
}

// ---------------------------------------------------------------------------
// Split group barrier (proven round 4): arrival = own-slot agent store
// (64B-spread); wait = wave-0 lanes poll group slots in parallel.
// Barrier-independent work (prefetch + wih MFMAs) sits between arrive/wait.
// ---------------------------------------------------------------------------
__device__ __forceinline__ void bar_arrive(int* __restrict__ gslots, int lidx, int gen) {
  __syncthreads();
  if (threadIdx.x == 0)
    __hip_atomic_store(&gslots[lidx * 16], gen, __ATOMIC_RELAXED, __HIP_MEMORY_SCOPE_AGENT);
}

__device__ __forceinline__ void bar_wait(int* __restrict__ gslots, int gsize, int gen) {
  if ((int)threadIdx.x < gsize) {
    while (__hip_atomic_load(&gslots[threadIdx.x * 16], __ATOMIC_RELAXED, __HIP_MEMORY_SCOPE_AGENT) < gen)
      __builtin_amdgcn_s_sleep(1);
  }
  __syncthreads();
}

// ---------------------------------------------------------------------------
// Tile staging unit: one "half" = [16 rows][512 elems]. Cooperative across the
// block (256 thr x 4 chunks of 16B-bf16 output). LDS XOR-swizzled
// (byte ^= (row&7)<<4) so MFMA fragment reads (16 lanes @ row stride) are
// conflict-free. fp32 sources are converted to bf16 ONCE at commit.
// ---------------------------------------------------------------------------
struct Half8 { i32x4 t[8]; };

__device__ __forceinline__ void half_issue(Half8& st, const void* base, size_t off,
                                           int stride, int isbf) {
  const int tid = threadIdx.x;
  if (isbf) {
#pragma unroll
    for (int i = 0; i < 4; ++i) {
      const int c = tid + i * 256;
      const int r = c >> 6, cc = c & 63;
      st.t[i] = *(const i32x4*)((const short*)base + off + (size_t)r * stride + cc * 8);
    }
  } else {
#pragma unroll
    for (int i = 0; i < 4; ++i) {
      const int c = tid + i * 256;
      const int r = c >> 6, cc = c & 63;
      const float* p = (const float*)base + off + (size_t)r * stride + cc * 8;
      st.t[2 * i]     = *(const i32x4*)p;
      st.t[2 * i + 1] = *(const i32x4*)(p + 4);
    }
  }
}

__device__ __forceinline__ void half_commit(Half8& st, char* lds, int rowb, int hoffb, int isbf) {
  const int tid = threadIdx.x;
#pragma unroll
  for (int i = 0; i < 4; ++i) {
    const int c = tid + i * 256;
    const int r = c >> 6, cc = c & 63;
    const int wb = hoffb + (cc << 4);
    char* dst = lds + (size_t)r * rowb + (size_t)(wb ^ ((r & 7) << 4));
    if (isbf) *(i32x4*)dst = st.t[i];
    else {
      const float* f0 = (const float*)&st.t[2 * i];
      const float* f1 = (const float*)&st.t[2 * i + 1];
      bf16x8 v;
      v[0] = f2bf(f0[0]); v[1] = f2bf(f0[1]); v[2] = f2bf(f0[2]); v[3] = f2bf(f0[3]);
      v[4] = f2bf(f1[0]); v[5] = f2bf(f1[1]); v[6] = f2bf(f1[2]); v[7] = f2bf(f1[3]);
      *(bf16x8*)dst = v;
    }
  }
}

// Coherent h staging (sc0sc1 L1/L2-bypass; h written with agent stores).
__device__ __forceinline__ void h_issue(Half8& st, const short* __restrict__ src) {
  const int tid = threadIdx.x;
#pragma unroll
  for (int i = 0; i < 4; ++i) {
    const short* p = src + (size_t)(tid + i * 256) * 8;
    asm volatile("global_load_dwordx4 %0, %1, off sc0 sc1" : "=v"(st.t[i]) : "v"(p));
  }
}
__device__ __forceinline__ void h_commit(Half8& st, short* __restrict__ hs) {
  const int tid = threadIdx.x;
  asm volatile("s_waitcnt vmcnt(0)" ::: "memory");
  __builtin_amdgcn_sched_barrier(0);
#pragma unroll
  for (int i = 0; i < 4; ++i) {
    const int c = tid + i * 256;
    const int r = c >> 6, wb = (c & 63) << 4;
    *(i32x4*)((char*)hs + (size_t)r * 1024 + (size_t)(wb ^ ((r & 7) << 4))) = st.t[i];
  }
}

// Swizzled LDS fragment read: row r, elem offset kk, row pitch in elems.
__device__ __forceinline__ bf16x8 frag(const short* __restrict__ lds, int pitch_e, int r, int kk) {
  return *(const bf16x8*)(lds + r * pitch_e + (kk ^ ((r & 7) << 3)));
}

// ---------------------------------------------------------------------------
// Elementwise convert-to-bf16 (Plan A: x -> x_bf). Copies if already bf16.
// ---------------------------------------------------------------------------
__global__ __launch_bounds__(256) void conv_bf16(const void* __restrict__ src,
                                                 __hip_bfloat16* __restrict__ dst,
                                                 const int* __restrict__ flagp,
                                                 size_t n8) {
  const int isbf = flagp[0];
  for (size_t i = (size_t)blockIdx.x * 256 + threadIdx.x; i < n8;
       i += (size_t)gridDim.x * 256) {
    bf16x8 v = ldab(src, i * 8, isbf);
    *(bf16x8*)((short*)dst + i * 8) = v;
  }
}

// ---------------------------------------------------------------------------
// Stash fill (Plans B/C/D): snapshot hazard halves of this pass's b-columns
// from pristine y0 (in out) into bf16 stash.
// ---------------------------------------------------------------------------
__global__ __launch_bounds__(256) void stash_fill(
    const void* __restrict__ out,
    __hip_bfloat16* __restrict__ stashF,
    __hip_bfloat16* __restrict__ stashB,
    const int* __restrict__ flagp,
    int bcount, int pass_off)
{
  const int isbf = flagp[0];
  const size_t total8 = (size_t)2 * 256 * bcount * HH / 8;
  for (size_t i = (size_t)blockIdx.x * 256 + threadIdx.x; i < total8;
       i += (size_t)gridDim.x * 256) {
    const size_t idx = i * 8;
    const int k = (int)(idx & 511);
    const size_t r = idx >> 9;
    const int lb = (int)(r % bcount);
    const size_t rr = r / bcount;
    const int row = (int)(rr & 255);
    const bool isB = rr >= 256;
    const size_t src = ((size_t)(isB ? (256 + row) : row) * BB + pass_off + lb) * 1024 +
                       (isB ? HH : 0) + k;
    bf16x8 v = ldab(out, src, isbf);
    __hip_bfloat16* dst = (isB ? stashB : stashF) + ((size_t)row * bcount + lb) * HH + k;
    *(bf16x8*)(void*)dst = v;
  }
}

// ---------------------------------------------------------------------------
// PERSISTENT LAYER 0. Grid 256 = dir(2) x jtile(32) x bq(4), 256 thr.
// 16 batches/block, 1 acc/wave. Weights in AGPRs; x tile double-buffered in
// LDS, prefetched one step ahead; h exchanged coherently. 1 barrier/step,
// groups (d,bq) of 32.
// ---------------------------------------------------------------------------
template<int ISBF, int USE_XBF>
__global__ __launch_bounds__(256, 1) void l0_persist(
    const void* __restrict__ x,
    const __hip_bfloat16* __restrict__ xbf,
    const void* __restrict__ Wih_f, const void* __restrict__ Whh_f, const void* __restrict__ bias_f,
    const void* __restrict__ Wih_b, const void* __restrict__ Whh_b, const void* __restrict__ bias_b,
    __hip_bfloat16* __restrict__ hbuf,   // [2 par][2 dir][64][512] bf16
    const int* __restrict__ lens,
    void* __restrict__ ydst,             // Plan A: y0_bf (bf16); else out (dtype)
    const int* __restrict__ flagp,
    int* __restrict__ slots)
{
  if (flagp[0] != ISBF) return;

  const int bx = blockIdx.x;
  const int d  = bx >> 7;
  const int jt = (bx >> 2) & 31;
  const int bq = bx & 3;
  int* gslots = slots + (d * 4 + bq) * 1024;
  const int lidx = jt;

  const void* Wih  = d ? Wih_b  : Wih_f;
  const void* Whh  = d ? Whh_b  : Whh_f;
  const void* bias = d ? bias_b : bias_f;

  const int tid  = threadIdx.x;
  const int lane = tid & 63;
  const int g    = tid >> 6;          // wave = gate (i,f,g,o)
  const int nm   = lane & 15;
  const int kq   = (lane >> 4) * 8;

  // ---- one-time: weights -> AGPRs ----
  bf16x8 wih[16], whh[16];
  {
    const size_t arow = (size_t)(g * HH + jt * 16 + nm) * HH + kq;
#pragma unroll
    for (int ks = 0; ks < 16; ++ks) {
      wih[ks] = ldab(Wih, arow + ks * 32, ISBF);
      whh[ks] = ldab(Whh, arow + ks * 32, ISBF);
    }
  }

  const void* xs = USE_XBF ? (const void*)xbf : x;
  const int   XF = USE_XBF ? 1 : ISBF;
  const int  YBF = USE_XBF ? 1 : ISBF;

  const int ub  = tid >> 4;              // local batch 0..15
  const int jq  = tid & 15;
  const int b_g = bq * 16 + ub;
  const int j_g = jt * 16 + jq;
  const int len = lens[b_g];
  float bias_r[4];
#pragma unroll
  for (int q = 0; q < 4; ++q) bias_r[q] = ldsc(bias, q * HH + j_g, ISBF);
  float c0 = 0.f;

  __shared__ float gx[4][16][17];
  __shared__ __align__(16) short hs[16 * HH];
  __shared__ __align__(16) short xt[2][16 * HH];

  const size_t hrow0 = (size_t)(bq * 16) * HH;   // within dir slice

  // prologue: stage x tile for s=0
  {
    Half8 p0;
    const int t0 = d ? (TT - 1) : 0;
    half_issue(p0, xs, ((size_t)t0 * BB + bq * 16) * HH, HH, XF);
    half_commit(p0, (char*)xt[0], 1024, 0, XF);
    __syncthreads();
  }
  int cur = 0;

  for (int s = 0; s < TT; ++s) {
    const int t_eff = d ? (TT - 1 - s) : s;
    const bool havepf = (s + 1 < TT);
    Half8 pf;
    if (havepf) {
      const int tn2 = d ? (TT - 2 - s) : (s + 1);
      half_issue(pf, xs, ((size_t)tn2 * BB + bq * 16) * HH, HH, XF);
    }
    f32x4 accA = {0.f, 0.f, 0.f, 0.f};
    f32x4 accB = {0.f, 0.f, 0.f, 0.f};
    const short* xc = xt[cur];
#pragma unroll
    for (int ks = 0; ks < 16; ks += 2) {
      accA = mfma_a(wih[ks],     frag(xc, 512, nm, kq + ks * 32), accA);
      accB = mfma_a(wih[ks + 1], frag(xc, 512, nm, kq + (ks + 1) * 32), accB);
    }
    bar_wait(gslots, 32, s);                 // h(s) now group-visible
    Half8 hsb;
    const short* hsrc = (const short*)hbuf + ((size_t)(s & 1) * 2 + d) * (size_t)(BB * HH) + hrow0;
    h_issue(hsb, hsrc);
    h_commit(hsb, hs);
    __syncthreads();
#pragma unroll
    for (int ks = 0; ks < 16; ks += 2) {
      accA = mfma_a(whh[ks],     frag(hs, 512, nm, kq + ks * 32), accA);
      accB = mfma_a(whh[ks + 1], frag(hs, 512, nm, kq + (ks + 1) * 32), accB);
    }
    mfma_fence(accA, accB);
    {
      const int quad = lane >> 4;
#pragma unroll
      for (int r = 0; r < 4; ++r)
        gx[g][quad * 4 + r][nm] = accA[r] + accB[r];
    }
    __syncthreads();

    // ---- fused update (1 elem/thread) ----
    {
      const float m = (t_eff < len) ? 1.0f : 0.0f;
      const int tn = d ? (t_eff - 1) : (t_eff + 1);
      const float mn = (tn >= 0 && tn < len) ? 1.0f : 0.0f;
      float vi = gx[0][jq][ub] + bias_r[0];
      float vf = gx[1][jq][ub] + bias_r[1];
      float vg = gx[2][jq][ub] + bias_r[2];
      float vo = gx[3][jq][ub] + bias_r[3];
      const float cold = c0 * m;
      const float c2 = sigf(vf) * cold + sigf(vi) * tanhfast(vg);
      const float hv = sigf(vo) * tanhfast(c2);
      c0 = c2;
      unsigned short hu = (unsigned short)f2bf(hv * mn);
      int other = __shfl_xor((int)hu, 1);
      if (!(tid & 1)) {
        unsigned int hp = (unsigned int)hu | ((unsigned int)(unsigned short)other << 16);
        unsigned int* hnxt = (unsigned int*)((short*)hbuf +
            ((size_t)((s + 1) & 1) * 2 + d) * (size_t)(BB * HH) + (size_t)b_g * HH + j_g);
        __hip_atomic_store(hnxt, hp, __ATOMIC_RELAXED, __HIP_MEMORY_SCOPE_AGENT);
      }
      const size_t yb = ((size_t)t_eff * BB + b_g) * 1024 + (size_t)d * HH + j_g;
      if (YBF) {
        unsigned short yu = (unsigned short)f2bf(hv * m);
        int yo = __shfl_xor((int)yu, 1);
        if (!(tid & 1))
          *(unsigned int*)((short*)ydst + yb) =
              (unsigned int)yu | ((unsigned int)(unsigned short)yo << 16);
      } else {
        ((float*)ydst)[yb] = hv * m;
      }
    }
    if (havepf) half_commit(pf, (char*)xt[cur ^ 1], 1024, 0, XF);
    if (s != TT - 1) bar_arrive(gslots, lidx, s + 1);
    cur ^= 1;
  }
}

// ---------------------------------------------------------------------------
// PERSISTENT LAYER 1. Grid 2 x 32 x nbq (nbq = bcount/16). 16 batches/block.
// Weights in AGPRs (192 frags). y tile [16][1024] double-buffered in LDS,
// prefetched one step ahead (pristine/stash sources need no barrier; row
// collision with deferred flushes is impossible: d=0 owns lo halves, d=1 hi,
// and row equality solves to s=255.5). In-place: out writes deferred one step
// (flush after next bar_wait) -> 1 barrier/step. Groups: Plan A (d,bq) x32;
// in-place bq x64 (dirs couple via out rows).
// ---------------------------------------------------------------------------
template<int ISBF, int USE_Y0>
__global__ __launch_bounds__(256, 1) void l1_persist(
    const void* __restrict__ Wih_f, const void* __restrict__ Whh_f, const void* __restrict__ bias_f,
    const void* __restrict__ Wih_b, const void* __restrict__ Whh_b, const void* __restrict__ bias_b,
    const void* __restrict__ ysrc,   // out (in-place) or y0_bf (Plan A)
    const __hip_bfloat16* __restrict__ stashF,
    const __hip_bfloat16* __restrict__ stashB,
    __hip_bfloat16* __restrict__ hbuf,
    const int* __restrict__ lens,
    void* __restrict__ out,
    const int* __restrict__ flagp,
    int* __restrict__ slots,
    int pass_off, int bcount)
{
  if (flagp[0] != ISBF) return;

  const int nbq = bcount >> 4;
  const int bx = blockIdx.x;
  const int d   = bx / (32 * nbq);
  const int rem = bx % (32 * nbq);
  const int jt  = rem / nbq;
  const int bq  = rem % nbq;

  int* gslots; int lidx, gsize;
  if (USE_Y0) { gslots = slots + (d * nbq + bq) * 1024; lidx = jt;          gsize = 32; }
  else        { gslots = slots + bq * 1024;             lidx = d * 32 + jt; gsize = 64; }

  const void* Wih  = d ? Wih_b  : Wih_f;
  const void* Whh  = d ? Whh_b  : Whh_f;
  const void* bias = d ? bias_b : bias_f;

  const int tid  = threadIdx.x;
  const int lane = tid & 63;
  const int g    = tid >> 6;
  const int nm   = lane & 15;
  const int kq   = (lane >> 4) * 8;

  // ---- one-time: weights -> AGPRs ----
  bf16x8 wih[32], whh[16];
  {
    const size_t arow_ih = (size_t)(g * HH + jt * 16 + nm) * 1024 + kq;
    const size_t arow_hh = (size_t)(g * HH + jt * 16 + nm) * HH + kq;
#pragma unroll
    for (int ks = 0; ks < 32; ++ks) wih[ks] = ldab(Wih, arow_ih + ks * 32, ISBF);
#pragma unroll
    for (int ks = 0; ks < 16; ++ks) whh[ks] = ldab(Whh, arow_hh + ks * 32, ISBF);
  }

  const int SRCF = USE_Y0 ? 1 : ISBF;
  const int ub  = tid >> 4;
  const int jq  = tid & 15;
  const int b_g = pass_off + bq * 16 + ub;
  const int j_g = jt * 16 + jq;
  const int len = lens[b_g];
  float bias_r[4];
#pragma unroll
  for (int q = 0; q < 4; ++q) bias_r[q] = ldsc(bias, q * HH + j_g, ISBF);
  float c0 = 0.f;

  __shared__ float gx[4][16][17];
  __shared__ __align__(16) short hs[16 * HH];
  __shared__ __align__(16) short yt[2][16 * 1024];

  const size_t hrow0 = (size_t)(pass_off + bq * 16) * HH;  // within dir slice

  // wave-uniform source resolver for step sN's y tile
  auto resolve = [&](int sN, const void*& pl, size_t& ol, int& stl, int& fl,
                     const void*& ph, size_t& oh, int& sth, int& fh) {
    const int t = d ? (TT - 1 - sN) : sN;
    const size_t rowbase = ((size_t)t * BB + pass_off + bq * 16) * 1024;
    if (d == 0) {
      pl = ysrc; ol = rowbase; stl = 1024; fl = SRCF;
      if (USE_Y0 || sN < 256) { ph = ysrc; oh = rowbase + HH; sth = 1024; fh = SRCF; }
      else { ph = stashB; oh = ((size_t)(sN - 256) * bcount + bq * 16) * HH; sth = HH; fh = 1; }
    } else {
      ph = ysrc; oh = rowbase + HH; sth = 1024; fh = SRCF;
      if (USE_Y0 || sN < 256) { pl = ysrc; ol = rowbase; stl = 1024; fl = SRCF; }
      else { pl = stashF; ol = ((size_t)t * bcount + bq * 16) * HH; stl = HH; fl = 1; }
    }
  };

  // prologue: stage y tile for s=0
  {
    const void* pl; size_t ol; int stl, fl; const void* ph; size_t oh; int sth, fh;
    resolve(0, pl, ol, stl, fl, ph, oh, sth, fh);
    Half8 a, b2;
    half_issue(a,  pl, ol, stl, fl);
    half_issue(b2, ph, oh, sth, fh);
    half_commit(a,  (char*)yt[0], 2048, 0,    fl);
    half_commit(b2, (char*)yt[0], 2048, 1024, fh);
    __syncthreads();
  }
  int cur = 0;
  int pend_t = -1; float pend0 = 0.f;

  for (int s = 0; s < TT; ++s) {
    const int t_eff = d ? (TT - 1 - s) : s;
    const bool havepf = (s + 1 < TT);
    Half8 pfa, pfb;
    int pfl = 1, pfh = 1;
    if (havepf) {
      const void* pl; size_t ol; int stl; const void* ph; size_t oh; int sth;
      resolve(s + 1, pl, ol, stl, pfl, ph, oh, sth, pfh);
      half_issue(pfa, pl, ol, stl, pfl);
      half_issue(pfb, ph, oh, sth, pfh);
    }
    f32x4 accA = {0.f, 0.f, 0.f, 0.f};
    f32x4 accB = {0.f, 0.f, 0.f, 0.f};
    const short* yc = yt[cur];
#pragma unroll
    for (int ks = 0; ks < 32; ks += 2) {
      accA = mfma_a(wih[ks],     frag(yc, 1024, nm, kq + ks * 32), accA);
      accB = mfma_a(wih[ks + 1], frag(yc, 1024, nm, kq + (ks + 1) * 32), accB);
    }
    bar_wait(gslots, gsize, s);              // h(s) visible; reads of row s-1 done
    Half8 hsb;
    const short* hsrc = (const short*)hbuf + ((size_t)(s & 1) * 2 + d) * (size_t)(BB * HH) + hrow0;
    h_issue(hsb, hsrc);
    // flush deferred out element (in-place) under the h round-trip shadow
    if (!USE_Y0 && pend_t >= 0) {
      const size_t yb = ((size_t)pend_t * BB + b_g) * 1024 + (size_t)d * HH + j_g;
      if (ISBF) ((__hip_bfloat16*)out)[yb] = __float2bfloat16(pend0);
      else      ((float*)out)[yb] = pend0;
    }
    h_commit(hsb, hs);
    __syncthreads();
#pragma unroll
    for (int ks = 0; ks < 16; ks += 2) {
      accA = mfma_a(whh[ks],     frag(hs, 512, nm, kq + ks * 32), accA);
      accB = mfma_a(whh[ks + 1], frag(hs, 512, nm, kq + (ks + 1) * 32), accB);
    }
    mfma_fence(accA, accB);
    {
      const int quad = lane >> 4;
#pragma unroll
      for (int r = 0; r < 4; ++r)
        gx[g][quad * 4 + r][nm] = accA[r] + accB[r];
    }
    __syncthreads();

    // ---- fused update: h store now, out write deferred (in-place) ----
    {
      const float m = (t_eff < len) ? 1.0f : 0.0f;
      const int tn = d ? (t_eff - 1) : (t_eff + 1);
      const float mn = (tn >= 0 && tn < len) ? 1.0f : 0.0f;
      float vi = gx[0][jq][ub] + bias_r[0];
      float vf = gx[1][jq][ub] + bias_r[1];
      float vg = gx[2][jq][ub] + bias_r[2];
      float vo = gx[3][jq][ub] + bias_r[3];
      const float cold = c0 * m;
      const float c2 = sigf(vf) * cold + sigf(vi) * tanhfast(vg);
      const float hv = sigf(vo) * tanhfast(c2);
      c0 = c2;
      unsigned short hu = (unsigned short)f2bf(hv * mn);
      int other = __shfl_xor((int)hu, 1);
      if (!(tid & 1)) {
        unsigned int hp = (unsigned int)hu | ((unsigned int)(unsigned short)other << 16);
        unsigned int* hnxt = (unsigned int*)((short*)hbuf +
            ((size_t)((s + 1) & 1) * 2 + d) * (size_t)(BB * HH) + (size_t)b_g * HH + j_g);
        __hip_atomic_store(hnxt, hp, __ATOMIC_RELAXED, __HIP_MEMORY_SCOPE_AGENT);
      }
      if (USE_Y0) {
        const size_t yb = ((size_t)t_eff * BB + b_g) * 1024 + (size_t)d * HH + j_g;
        if (ISBF) {
          unsigned short yu = (unsigned short)f2bf(hv * m);
          int yo = __shfl_xor((int)yu, 1);
          if (!(tid & 1))
            *(unsigned int*)((short*)out + yb) =
                (unsigned int)yu | ((unsigned int)(unsigned short)yo << 16);
        } else {
          ((float*)out)[yb] = hv * m;
        }
      } else {
        pend0 = hv * m; pend_t = t_eff;
      }
    }
    if (havepf) {
      half_commit(pfa, (char*)yt[cur ^ 1], 2048, 0,    pfl);
      half_commit(pfb, (char*)yt[cur ^ 1], 2048, 1024, pfh);
    }
    if (s != TT - 1) bar_arrive(gslots, lidx, s + 1);
    cur ^= 1;
  }

  // final deferred flush (in-place)
  if (!USE_Y0 && pend_t >= 0) {
    const size_t yb = ((size_t)pend_t * BB + b_g) * 1024 + (size_t)d * HH + j_g;
    if (ISBF) ((__hip_bfloat16*)out)[yb] = __float2bfloat16(pend0);
    else      ((float*)out)[yb] = pend0;
  }
}

// ---------------------------------------------------------------------------
extern "C" void kernel_launch(void* const* d_in, const int* in_sizes, int n_in,
                              void* d_out, int out_size, void* d_ws, size_t ws_size,
                              hipStream_t stream) {
  (void)in_sizes; (void)n_in; (void)out_size;
  const void* x     = d_in[0];
  const int*  lens  = (const int*)d_in[1];
  const void* fWih0 = d_in[2];
  const void* fWhh0 = d_in[3];
  const void* fb0   = d_in[4];
  const void* bWih0 = d_in[5];
  const void* bWhh0 = d_in[6];
  const void* bb0   = d_in[7];
  const void* fWih1 = d_in[8];
  const void* fWhh1 = d_in[9];
  const void* fb1   = d_in[10];
  const void* bWih1 = d_in[11];
  const void* bWhh1 = d_in[12];
  const void* bb1   = d_in[13];
  void* out = d_out;

  // --- ws layout: [flag @0][slots 32KB @4096][hb @65536][dyn] ---
  char* w = (char*)d_ws;
  int* flagp = (int*)w;
  int* slots = (int*)(w + 4096);
  __hip_bfloat16* hb = (__hip_bfloat16*)(w + 65536);
  const size_t HBYTES = (size_t)2 * 2 * BB * HH * sizeof(__hip_bfloat16); // 256 KiB
  char* dyn = w + 65536 + HBYTES;
  const size_t avail = (ws_size > 65536 + HBYTES) ? (ws_size - 65536 - HBYTES) : 0;

  const size_t XBF = (size_t)TT * BB * HH * 2;     // 32 MB bf16 x
  const size_t Y0B = (size_t)TT * BB * 1024 * 2;   // 64 MB bf16 y0

  sniff<<<1, 256, 0, stream>>>((const unsigned int*)x, flagp);

  if (avail >= XBF + Y0B) {
    // ---- Plan A: separate bf16 y0; out never read in l1 ----
    __hip_bfloat16* xbf = (__hip_bfloat16*)dyn;
    __hip_bfloat16* y0  = (__hip_bfloat16*)(dyn + XBF);
    conv_bf16<<<2048, 256, 0, stream>>>(x, xbf, flagp, (size_t)TT * BB * HH / 8);
    hipMemsetAsync(hb, 0, HBYTES, stream);
    hipMemsetAsync(w + 4096, 0, 32768, stream);
    l0_persist<0, 1><<<256, 256, 0, stream>>>(x, xbf, fWih0, fWhh0, fb0, bWih0, bWhh0, bb0,
                                              hb, lens, y0, flagp, slots);
    l0_persist<1, 1><<<256, 256, 0, stream>>>(x, xbf, fWih0, fWhh0, fb0, bWih0, bWhh0, bb0,
                                              hb, lens, y0, flagp, slots);
    hipMemsetAsync(hb, 0, HBYTES, stream);
    hipMemsetAsync(w + 4096, 0, 32768, stream);
    l1_persist<0, 1><<<256, 256, 0, stream>>>(fWih1, fWhh1, fb1, bWih1, bWhh1, bb1,
                                              y0, nullptr, nullptr, hb, lens, out,
                                              flagp, slots, 0, 64);
    l1_persist<1, 1><<<256, 256, 0, stream>>>(fWih1, fWhh1, fb1, bWih1, bWhh1, bb1,
                                              y0, nullptr, nullptr, hb, lens, out,
                                              flagp, slots, 0, 64);
  } else {
    // ---- Plans B/C/D: in-place out + bf16 stash of hazard halves ----
    const int bcount = (avail >= (size_t)64 * 524288) ? 64 :
                       (avail >= (size_t)32 * 524288) ? 32 : 16;
    __hip_bfloat16* stashF = (__hip_bfloat16*)dyn;
    __hip_bfloat16* stashB = stashF + (size_t)256 * bcount * HH;

    hipMemsetAsync(hb, 0, HBYTES, stream);
    hipMemsetAsync(w + 4096, 0, 32768, stream);
    l0_persist<0, 0><<<256, 256, 0, stream>>>(x, nullptr, fWih0, fWhh0, fb0, bWih0, bWhh0, bb0,
                                              hb, lens, out, flagp, slots);
    l0_persist<1, 0><<<256, 256, 0, stream>>>(x, nullptr, fWih0, fWhh0, fb0, bWih0, bWhh0, bb0,
                                              hb, lens, out, flagp, slots);
    const int P = 64 / bcount;
    for (int p = 0; p < P; ++p) {
      stash_fill<<<1024, 256, 0, stream>>>(out, stashF, stashB, flagp, bcount, p * bcount);
      hipMemsetAsync(hb, 0, HBYTES, stream);
      hipMemsetAsync(w + 4096, 0, 32768, stream);
      l1_persist<0, 0><<<2 * 32 * (bcount / 16), 256, 0, stream>>>(
          fWih1, fWhh1, fb1, bWih1, bWhh1, bb1,
          out, stashF, stashB, hb, lens, out, flagp, slots, p * bcount, bcount);
      l1_persist<1, 0><<<2 * 32 * (bcount / 16), 256, 0, stream>>>(
          fWih1, fWhh1, fb1, bWih1, bWhh1, bb1,
          out, stashF, stashB, hb, lens, out, flagp, slots, p * bcount, bcount);
    }
  }
}